// Round 11
// baseline (287.115 us; speedup 1.0000x reference)
//
#include <hip/hip_runtime.h>
#include <hip/hip_fp16.h>
#include <math.h>

#define N_NODES 100000
#define N_EDGES 1600000
#define NEG_SLOPE 0.2f
#define EPS 1e-16f

// bucket sort geometry: 196 buckets of 512 nodes; 391 blocks x 4096 edges
#define NBUCK 196
#define CHUNK 4096
#define BLKB 391

__device__ __forceinline__ float lrelu(float v) { return v > 0.f ? v : NEG_SLOPE * v; }

// load 4 halfs -> float4 (single 8B load)
__device__ __forceinline__ float4 ld4h(const __half* p) {
    uint2 r = *(const uint2*)p;
    __half2 h0 = *reinterpret_cast<const __half2*>(&r.x);
    __half2 h1 = *reinterpret_cast<const __half2*>(&r.y);
    float2 f0 = __half22float2(h0), f1 = __half22float2(h1);
    return make_float4(f0.x, f0.y, f1.x, f1.y);
}

// load 8 halfs -> 8 floats (single 16B load)
__device__ __forceinline__ void ld8h(const __half* p, float* f) {
    uint4 r = *(const uint4*)p;
    __half2 h0 = *reinterpret_cast<const __half2*>(&r.x);
    __half2 h1 = *reinterpret_cast<const __half2*>(&r.y);
    __half2 h2 = *reinterpret_cast<const __half2*>(&r.z);
    __half2 h3 = *reinterpret_cast<const __half2*>(&r.w);
    float2 f0 = __half22float2(h0), f1 = __half22float2(h1);
    float2 f2 = __half22float2(h2), f3 = __half22float2(h3);
    f[0] = f0.x; f[1] = f0.y; f[2] = f1.x; f[3] = f1.y;
    f[4] = f2.x; f[5] = f2.y; f[6] = f3.x; f[7] = f3.y;
}

// ---------------------------------------------------------------- Pass A: per-block coarse histogram (LDS only)
__global__ void kA_hist(const int* __restrict__ ei, int* __restrict__ bh) {
    __shared__ int hist[NBUCK];
    int tid = threadIdx.x, b = blockIdx.x;
    if (tid < NBUCK) hist[tid] = 0;
    __syncthreads();
    int base = b * CHUNK;
    #pragma unroll
    for (int i = 0; i < CHUNK / 256; i++) {
        int e = base + i * 256 + tid;
        if (e < N_EDGES) {
            int dst = ei[N_EDGES + e];
            atomicAdd(&hist[dst >> 9], 1);
        }
    }
    __syncthreads();
    if (tid < NBUCK) bh[b * NBUCK + tid] = hist[tid];
}

// ---------------------------------------------------------------- S1: column scan of bh (one block per bucket)
__global__ void kS1(int* __restrict__ bh, int* __restrict__ bucketStart) {
    __shared__ int tsum[256];
    int k = blockIdx.x, t = threadIdx.x;
    int j0 = 2 * t, j1 = 2 * t + 1;
    int v0 = (j0 < BLKB) ? bh[j0 * NBUCK + k] : 0;
    int v1 = (j1 < BLKB) ? bh[j1 * NBUCK + k] : 0;
    int s = v0 + v1;
    tsum[t] = s;
    __syncthreads();
    for (int off = 1; off < 256; off <<= 1) {
        int tv = (t >= off) ? tsum[t - off] : 0;
        __syncthreads();
        tsum[t] += tv;
        __syncthreads();
    }
    int excl = tsum[t] - s;
    if (j0 < BLKB) bh[j0 * NBUCK + k] = excl;
    if (j1 < BLKB) bh[j1 * NBUCK + k] = excl + v0;
    if (t == 255) bucketStart[k] = tsum[255];   // column total (scanned by S2)
}

// ---------------------------------------------------------------- S2: scan bucket totals -> bucket starts (+ total at [NBUCK])
__global__ void kS2(int* __restrict__ bucketStart) {
    __shared__ int tmp[256];
    int t = threadIdx.x;
    int v = (t < NBUCK) ? bucketStart[t] : 0;
    tmp[t] = v;
    __syncthreads();
    for (int off = 1; off < 256; off <<= 1) {
        int tv = (t >= off) ? tmp[t - off] : 0;
        __syncthreads();
        tmp[t] += tv;
        __syncthreads();
    }
    if (t < NBUCK) bucketStart[t] = tmp[t] - v;
    if (t == NBUCK - 1) bucketStart[NBUCK] = tmp[t];
}

// ---------------------------------------------------------------- Pass B: bin edges by coarse bucket (LDS cursors, coalesced-run writes)
__global__ void kB_bin(const int* __restrict__ ei, const int* __restrict__ bh,
                       const int* __restrict__ bucketStart, int* __restrict__ binned) {
    __shared__ int cur[NBUCK];
    int tid = threadIdx.x, b = blockIdx.x;
    if (tid < NBUCK) cur[tid] = bucketStart[tid] + bh[b * NBUCK + tid];
    __syncthreads();
    int base = b * CHUNK;
    #pragma unroll
    for (int i = 0; i < CHUNK / 256; i++) {
        int e = base + i * 256 + tid;
        if (e < N_EDGES) {
            int src = ei[e], dst = ei[N_EDGES + e];
            int pos = atomicAdd(&cur[dst >> 9], 1);
            binned[pos] = src | ((dst & 511) << 17);
        }
    }
}

// ---------------------------------------------------------------- Pass C: per-bucket counting sort -> deg, rowptr, csr_src
__global__ void kC_sort(const int* __restrict__ bucketStart, const int* __restrict__ binned,
                        int* __restrict__ deg, int* __restrict__ rowptr,
                        int* __restrict__ csr_src) {
    __shared__ int cnt[512];
    __shared__ int pfx[512];
    __shared__ int bsum[256];
    int t = threadIdx.x, k = blockIdx.x;
    int s0 = bucketStart[k], s1 = bucketStart[k + 1];
    cnt[t] = 0; cnt[t + 256] = 0;
    __syncthreads();
    for (int i = s0 + t; i < s1; i += 256)
        atomicAdd(&cnt[binned[i] >> 17], 1);
    __syncthreads();
    int a0 = cnt[2 * t], a1 = cnt[2 * t + 1];
    int s = a0 + a1;
    bsum[t] = s;
    __syncthreads();
    for (int off = 1; off < 256; off <<= 1) {
        int tv = (t >= off) ? bsum[t - off] : 0;
        __syncthreads();
        bsum[t] += tv;
        __syncthreads();
    }
    int excl = bsum[t] - s;
    pfx[2 * t] = excl;
    pfx[2 * t + 1] = excl + a0;
    int nb0 = k << 9;
    int n0 = nb0 + 2 * t, n1 = nb0 + 2 * t + 1;
    if (n0 < N_NODES) { deg[n0] = a0; rowptr[n0] = s0 + excl; }
    if (n1 < N_NODES) { deg[n1] = a1; rowptr[n1] = s0 + excl + a0; }
    __syncthreads();
    for (int i = s0 + t; i < s1; i += 256) {
        int pkd = binned[i];
        int pos = s0 + atomicAdd(&pfx[pkd >> 17], 1);
        csr_src[pos] = pkd & 0x1FFFF;
    }
}

// ---------------------------------------------------------------- K-Q: qs[h] = W1_h^T a_src_h, qd[h] = W1_h^T a_dst_h  (24 floats)
__global__ void k_q(const float* __restrict__ w1, const float* __restrict__ as1,
                    const float* __restrict__ ad1, float* __restrict__ qv) {
    int t = threadIdx.x;
    if (t >= 24) return;
    int c = t % 3, h = (t / 3) % 4, side = t / 12;
    const float* att = side ? ad1 : as1;
    float acc = 0.f;
    for (int cc = 0; cc < 32; cc++)
        acc += att[h * 32 + cc] * w1[(h * 32 + cc) * 3 + c];
    qv[t] = acc;
}

// ---------------------------------------------------------------- K-NODE1: a1d = x.qd ; p1[n] = {a1s[4], x0,x1,x2,1} (32B row)
__global__ void k_node1(const float* __restrict__ x, const float* __restrict__ qv,
                        float* __restrict__ a1d, float* __restrict__ p1) {
    int n = blockIdx.x * blockDim.x + threadIdx.x;
    if (n >= N_NODES) return;
    float x0 = x[n * 3], x1 = x[n * 3 + 1], x2 = x[n * 3 + 2];
    float4 s, d;
    s.x = x0 * qv[0]  + x1 * qv[1]  + x2 * qv[2];
    s.y = x0 * qv[3]  + x1 * qv[4]  + x2 * qv[5];
    s.z = x0 * qv[6]  + x1 * qv[7]  + x2 * qv[8];
    s.w = x0 * qv[9]  + x1 * qv[10] + x2 * qv[11];
    d.x = x0 * qv[12] + x1 * qv[13] + x2 * qv[14];
    d.y = x0 * qv[15] + x1 * qv[16] + x2 * qv[17];
    d.z = x0 * qv[18] + x1 * qv[19] + x2 * qv[20];
    d.w = x0 * qv[21] + x1 * qv[22] + x2 * qv[23];
    ((float4*)a1d)[n] = d;
    ((float4*)p1)[n * 2]     = s;
    float4 xx; xx.x = x0; xx.y = x1; xx.z = x2; xx.w = 1.f;
    ((float4*)p1)[n * 2 + 1] = xx;
}

// ---------------------------------------------------------------- K-GAT1 v4: 16 lanes/node, 4 nodes/wave (k_gat2-v5 structure)
// Rounds 6/10 falsified the wave-supply theory (2x waves -> occupancy flat,
// time flat): phase-B's per-wave serial structure was the cost. v4
// parallelizes the dense part across the node's 16 lanes: w2 in LDS
// (132-float row stride; lane sl owns rows sl & sl+16 -> 2-way banks, free),
// per-lane f1 channels j=sl*8..+7 (w1/b1 in regs, loaded once), f1 staged in
// a per-node LDS row, one parallel 32-iter dot per node (was 8 serial nodes
// x 64-FMA each vs a 64-VGPR w2 block). Head sums stay in registers
// (sm[] LDS round-trip eliminated).
#define G1_BLOCKS ((N_NODES + 15) / 16)
__global__ void k_gat1(const int* __restrict__ rowptr, const int* __restrict__ deg,
                       const int* __restrict__ csr_src,
                       const float* __restrict__ p1, const float* __restrict__ w1,
                       const float* __restrict__ a1d,
                       const float* __restrict__ b1, const float* __restrict__ w2,
                       const float* __restrict__ as2, const float* __restrict__ ad2,
                       __half* __restrict__ h2, float* __restrict__ a2s, float* __restrict__ a2d) {
    __shared__ float Ws[32 * 132];    // w2 rows, 132-float stride (2-way banks on dot reads)
    __shared__ float F1[16][132];     // per (wave,group) f1 row
    int tid = threadIdx.x;
    for (int i = tid; i < 4096; i += 256) {
        int o = i >> 7, k = i & 127;
        Ws[o * 132 + k] = w2[i];
    }
    __syncthreads();
    int lane = tid & 63, w = tid >> 6;
    int nl = lane >> 4, sl = lane & 15;      // group (node) / sub-lane
    int g = w * 4 + nl;                      // F1 row (0..15)
    int n = blockIdx.x * 16 + g;             // 100000 = 16*6250: always < N_NODES

    // per-lane static data: f1 channels j = sl*8..sl*8+7 (head hh = sl>>2)
    float w1r[24], b1r[8];
    {
        const float4* wp = (const float4*)(w1 + sl * 24);   // 96B-aligned
        #pragma unroll
        for (int q = 0; q < 6; q++) {
            float4 t4 = wp[q];
            w1r[q * 4 + 0] = t4.x; w1r[q * 4 + 1] = t4.y;
            w1r[q * 4 + 2] = t4.z; w1r[q * 4 + 3] = t4.w;
        }
        const float4* bp = (const float4*)(b1 + sl * 8);
        float4 ta = bp[0], tb = bp[1];
        b1r[0] = ta.x; b1r[1] = ta.y; b1r[2] = ta.z; b1r[3] = ta.w;
        b1r[4] = tb.x; b1r[5] = tb.y; b1r[6] = tb.z; b1r[7] = tb.w;
    }
    float as2a = as2[sl], as2b = as2[sl + 16];
    float ad2a = ad2[sl], ad2b = ad2[sl + 16];

    // ---- phase A: 16 lanes partition this node's edges (stride 16), all 4 heads/lane
    float sA[4] = {0.f, 0.f, 0.f, 0.f};   // s0 per head
    float sB[4] = {0.f, 0.f, 0.f, 0.f};   // s1 per head
    float sC[4] = {0.f, 0.f, 0.f, 0.f};   // s2 per head
    float sD[4] = {0.f, 0.f, 0.f, 0.f};   // den per head
    if (n < N_NODES) {
        float4 ad4 = ((const float4*)a1d)[n];
        float adv[4] = {ad4.x, ad4.y, ad4.z, ad4.w};
        int beg = rowptr[n], cnt = deg[n];
        for (int t = sl; t < cnt; t += 16) {
            int i0 = csr_src[beg + t];
            float4 A0 = ((const float4*)p1)[i0 * 2], X0 = ((const float4*)p1)[i0 * 2 + 1];
            float av[4] = {A0.x, A0.y, A0.z, A0.w};
            #pragma unroll
            for (int hh = 0; hh < 4; hh++) {
                float e0 = __expf(lrelu(av[hh] + adv[hh]));
                sA[hh] += e0 * X0.x;
                sB[hh] += e0 * X0.y;
                sC[hh] += e0 * X0.z;
                sD[hh] += e0;
            }
        }
    }
    // 16-lane butterfly (group exec-uniform: same n) — all lanes get full sums
    #pragma unroll
    for (int hh = 0; hh < 4; hh++) {
        sA[hh] += __shfl_xor(sA[hh], 1); sA[hh] += __shfl_xor(sA[hh], 2);
        sA[hh] += __shfl_xor(sA[hh], 4); sA[hh] += __shfl_xor(sA[hh], 8);
        sB[hh] += __shfl_xor(sB[hh], 1); sB[hh] += __shfl_xor(sB[hh], 2);
        sB[hh] += __shfl_xor(sB[hh], 4); sB[hh] += __shfl_xor(sB[hh], 8);
        sC[hh] += __shfl_xor(sC[hh], 1); sC[hh] += __shfl_xor(sC[hh], 2);
        sC[hh] += __shfl_xor(sC[hh], 4); sC[hh] += __shfl_xor(sC[hh], 8);
        sD[hh] += __shfl_xor(sD[hh], 1); sD[hh] += __shfl_xor(sD[hh], 2);
        sD[hh] += __shfl_xor(sD[hh], 4); sD[hh] += __shfl_xor(sD[hh], 8);
    }
    // ---- f1 channels for this lane (head hh = sl>>2; static ternary select)
    {
        int hh = sl >> 2;
        float hs0 = hh == 0 ? sA[0] : hh == 1 ? sA[1] : hh == 2 ? sA[2] : sA[3];
        float hs1 = hh == 0 ? sB[0] : hh == 1 ? sB[1] : hh == 2 ? sB[2] : sB[3];
        float hs2 = hh == 0 ? sC[0] : hh == 1 ? sC[1] : hh == 2 ? sC[2] : sC[3];
        float hsd = hh == 0 ? sD[0] : hh == 1 ? sD[1] : hh == 2 ? sD[2] : sD[3];
        float inv = 1.f / (hsd + EPS);
        float f1v[8];
        #pragma unroll
        for (int i = 0; i < 8; i++) {
            float vv = (w1r[i * 3] * hs0 + w1r[i * 3 + 1] * hs1 + w1r[i * 3 + 2] * hs2) * inv
                       + b1r[i];
            f1v[i] = vv > 0.f ? vv : expm1f(vv);
        }
        float4 fa, fb;
        fa.x = f1v[0]; fa.y = f1v[1]; fa.z = f1v[2]; fa.w = f1v[3];
        fb.x = f1v[4]; fb.y = f1v[5]; fb.z = f1v[6]; fb.w = f1v[7];
        *(float4*)&F1[g][sl * 8]     = fa;   // same-wave stage, no barrier
        *(float4*)&F1[g][sl * 8 + 4] = fb;
    }
    // ---- dense: lane sl computes h2 rows sl and sl+16 (parallel across the node)
    float ra = 0.f, rb = 0.f;
    {
        const float* Wa = &Ws[sl * 132];
        const float* Wb = &Ws[(sl + 16) * 132];
        const float* Fr = &F1[g][0];
        #pragma unroll
        for (int q = 0; q < 32; q++) {
            float4 fq = *(const float4*)&Fr[q * 4];       // group broadcast
            float4 wa = *(const float4*)&Wa[q * 4];       // 2-way bank: free
            float4 wb = *(const float4*)&Wb[q * 4];
            ra += wa.x * fq.x + wa.y * fq.y + wa.z * fq.z + wa.w * fq.w;
            rb += wb.x * fq.x + wb.y * fq.y + wb.z * fq.z + wb.w * fq.w;
        }
    }
    if (n < N_NODES) {
        h2[n * 32 + sl]      = __float2half(ra);   // 16 lanes -> 32B segment
        h2[n * 32 + sl + 16] = __float2half(rb);
        float ps = ra * as2a + rb * as2b;
        float pd = ra * ad2a + rb * ad2b;
        ps += __shfl_xor(ps, 1); ps += __shfl_xor(ps, 2);
        ps += __shfl_xor(ps, 4); ps += __shfl_xor(ps, 8);
        pd += __shfl_xor(pd, 1); pd += __shfl_xor(pd, 2);
        pd += __shfl_xor(pd, 4); pd += __shfl_xor(pd, 8);
        if (sl == 0) { a2s[n] = ps; a2d[n] = pd; }
    }
}

// ---------------------------------------------------------------- K-GAT2 v5: 16 lanes/node, 4 nodes/wave (4x miss chains)
#define G2_BLOCKS ((N_NODES + 15) / 16)
__global__ void k_gat2(const int* __restrict__ rowptr, const int* __restrict__ deg,
                       const int* __restrict__ csr_src,
                       const __half* __restrict__ h2, const float* __restrict__ a2s,
                       const float* __restrict__ a2d, const float* __restrict__ b2,
                       const float* __restrict__ mw1, const float* __restrict__ mb1,
                       __half* __restrict__ u, __half* __restrict__ v) {
    __shared__ float Ws2[2][32 * 36];    // [half][c*36+k]; row start 144B (16B-aligned)
    __shared__ int2  pk[4][64];          // per-wave staged (idx, e-bits), 16 slots/group
    __shared__ float4 hfs[4][4][8];      // [wave][group][8 quads] = hf vector (32 floats)
    int tid = threadIdx.x;
    for (int i = tid; i < 2048; i += 256) {
        int c = i >> 6, col = i & 63;
        Ws2[col >> 5][c * 36 + (col & 31)] = mw1[i];
    }
    __syncthreads();
    int lane = tid & 63, w = tid >> 6;
    int nl = lane >> 4, sl = lane & 15;          // group (node) / sub-lane
    int eg2 = sl >> 2, qq = sl & 3;              // edge slot / 16-B chunk
    int n = blockIdx.x * 16 + w * 4 + nl;        // one node per group, no stride loop
    float4 b2a = ((const float4*)b2)[qq * 2];    // channels qq*8 .. qq*8+3
    float4 b2b = ((const float4*)b2)[qq * 2 + 1];// channels qq*8+4 .. qq*8+7

    int beg = 0, cnt = 0;
    float ad = 0.f;
    if (n < N_NODES) { beg = rowptr[n]; cnt = deg[n]; ad = a2d[n]; }

    float acc[8] = {0.f, 0.f, 0.f, 0.f, 0.f, 0.f, 0.f, 0.f};
    float den = 0.f;
    int pkbase = (nl << 4);
    for (int b16 = 0; b16 < cnt; b16 += 16) {    // group-divergent, exec-masked
        int li = b16 + sl;
        int idx = (li < cnt) ? csr_src[beg + li] : 0;
        float e = 0.f;
        if (li < cnt) e = __expf(lrelu(a2s[idx] + ad));
        den += e;
        pk[w][pkbase + sl] = make_int2(idx, __float_as_int(e)); // same-wave stage
        #pragma unroll
        for (int p = 0; p < 4; p++) {            // fixed 4 steps: 4 rows in flight/group
            int2 pe = pk[w][pkbase + p * 4 + eg2];
            float g[8];
            ld8h(h2 + pe.x * 32 + qq * 8, g);    // 16-B gather (8 halfs)
            float ee = __int_as_float(pe.y);     // 0 for pads
            acc[0] += ee * g[0]; acc[1] += ee * g[1];
            acc[2] += ee * g[2]; acc[3] += ee * g[3];
            acc[4] += ee * g[4]; acc[5] += ee * g[5];
            acc[6] += ee * g[6]; acc[7] += ee * g[7];
        }
    }
    // reduce across the 4 edge slots (within 16-lane group)
    #pragma unroll
    for (int j = 0; j < 8; j++) {
        float vv = acc[j];
        vv += __shfl_xor(vv, 4);
        vv += __shfl_xor(vv, 8);
        acc[j] = vv;
    }
    den += __shfl_xor(den, 1); den += __shfl_xor(den, 2);
    den += __shfl_xor(den, 4); den += __shfl_xor(den, 8);
    float inv = 1.f / (den + EPS);
    if (sl < 4) {                                // sl<4 => eg2=0, qq=sl
        float4 ha, hb;
        ha.x = acc[0] * inv + b2a.x; ha.y = acc[1] * inv + b2a.y;
        ha.z = acc[2] * inv + b2a.z; ha.w = acc[3] * inv + b2a.w;
        hb.x = acc[4] * inv + b2b.x; hb.y = acc[5] * inv + b2b.y;
        hb.z = acc[6] * inv + b2b.z; hb.w = acc[7] * inv + b2b.w;
        hfs[w][nl][qq * 2]     = ha;             // same-wave stage
        hfs[w][nl][qq * 2 + 1] = hb;
    }
    // epilogue: 16 lanes per node, 4 output channels per lane
    if (n < N_NODES) {
        int half_o = sl >> 3, c4 = (sl & 7) * 4;
        __half* outp = half_o ? v : u;
        float r0 = half_o ? 0.f : mb1[c4 + 0];
        float r1 = half_o ? 0.f : mb1[c4 + 1];
        float r2 = half_o ? 0.f : mb1[c4 + 2];
        float r3 = half_o ? 0.f : mb1[c4 + 3];
        const float* Wb = &Ws2[half_o][0];
        #pragma unroll
        for (int q = 0; q < 8; q++) {
            float4 hq = hfs[w][nl][q];           // broadcast within group
            float4 W0 = *(const float4*)&Wb[(c4 + 0) * 36 + q * 4];
            float4 W1 = *(const float4*)&Wb[(c4 + 1) * 36 + q * 4];
            float4 W2 = *(const float4*)&Wb[(c4 + 2) * 36 + q * 4];
            float4 W3 = *(const float4*)&Wb[(c4 + 3) * 36 + q * 4];
            r0 += W0.x * hq.x + W0.y * hq.y + W0.z * hq.z + W0.w * hq.w;
            r1 += W1.x * hq.x + W1.y * hq.y + W1.z * hq.z + W1.w * hq.w;
            r2 += W2.x * hq.x + W2.y * hq.y + W2.z * hq.z + W2.w * hq.w;
            r3 += W3.x * hq.x + W3.y * hq.y + W3.z * hq.z + W3.w * hq.w;
        }
        __half2 p0, p1;
        p0.x = __float2half(r0); p0.y = __float2half(r1);
        p1.x = __float2half(r2); p1.y = __float2half(r3);
        uint2 st;
        st.x = *reinterpret_cast<unsigned int*>(&p0);
        st.y = *reinterpret_cast<unsigned int*>(&p1);
        *reinterpret_cast<uint2*>(outp + n * 32 + c4) = st;  // 8-B aligned store
    }
}

// ---------------------------------------------------------------- K-MLP: 8 lanes/edge, 4 edges/iter, fp16 u/v rows (1 line each)
#define MLP_BLOCKS 4096
__global__ void k_mlp(const int* __restrict__ ei, const __half* __restrict__ u,
                      const __half* __restrict__ v, const float* __restrict__ mw2,
                      const float* __restrict__ mb2, float* __restrict__ out) {
    int tid = threadIdx.x;
    int q = tid & 7;
    float4 w2q = ((const float4*)mw2)[q];
    float mb20 = mb2[0];
    int g = blockIdx.x * 32 + (tid >> 3);
    const int stride = MLP_BLOCKS * 32 * 4;
    for (int e = g * 4; e < N_EDGES; e += stride) {
        int eb = e;
        int e1 = (eb + 1 < N_EDGES) ? eb + 1 : eb;
        int e2 = (eb + 2 < N_EDGES) ? eb + 2 : eb;
        int e3 = (eb + 3 < N_EDGES) ? eb + 3 : eb;
        int sa = ei[eb], da = ei[N_EDGES + eb];
        int sb = ei[e1], db = ei[N_EDGES + e1];
        int sc = ei[e2], dc = ei[N_EDGES + e2];
        int sd = ei[e3], dd = ei[N_EDGES + e3];
        float4 ua = ld4h(u + sa * 32 + q * 4);
        float4 va = ld4h(v + da * 32 + q * 4);
        float4 ub = ld4h(u + sb * 32 + q * 4);
        float4 vb = ld4h(v + db * 32 + q * 4);
        float4 uc = ld4h(u + sc * 32 + q * 4);
        float4 vc = ld4h(v + dc * 32 + q * 4);
        float4 ud = ld4h(u + sd * 32 + q * 4);
        float4 vd = ld4h(v + dd * 32 + q * 4);
        float s0 = fmaxf(ua.x + va.x, 0.f) * w2q.x + fmaxf(ua.y + va.y, 0.f) * w2q.y
                 + fmaxf(ua.z + va.z, 0.f) * w2q.z + fmaxf(ua.w + va.w, 0.f) * w2q.w;
        float s1 = fmaxf(ub.x + vb.x, 0.f) * w2q.x + fmaxf(ub.y + vb.y, 0.f) * w2q.y
                 + fmaxf(ub.z + vb.z, 0.f) * w2q.z + fmaxf(ub.w + vb.w, 0.f) * w2q.w;
        float s2 = fmaxf(uc.x + vc.x, 0.f) * w2q.x + fmaxf(uc.y + vc.y, 0.f) * w2q.y
                 + fmaxf(uc.z + vc.z, 0.f) * w2q.z + fmaxf(uc.w + vc.w, 0.f) * w2q.w;
        float s3 = fmaxf(ud.x + vd.x, 0.f) * w2q.x + fmaxf(ud.y + vd.y, 0.f) * w2q.y
                 + fmaxf(ud.z + vd.z, 0.f) * w2q.z + fmaxf(ud.w + vd.w, 0.f) * w2q.w;
        s0 += __shfl_xor(s0, 1, 8); s0 += __shfl_xor(s0, 2, 8); s0 += __shfl_xor(s0, 4, 8);
        s1 += __shfl_xor(s1, 1, 8); s1 += __shfl_xor(s1, 2, 8); s1 += __shfl_xor(s1, 4, 8);
        s2 += __shfl_xor(s2, 1, 8); s2 += __shfl_xor(s2, 2, 8); s2 += __shfl_xor(s2, 4, 8);
        s3 += __shfl_xor(s3, 1, 8); s3 += __shfl_xor(s3, 2, 8); s3 += __shfl_xor(s3, 4, 8);
        if (q == 0) {
            out[eb] = fmaxf(s0 + mb20, 0.f);
            if (eb + 1 < N_EDGES) out[eb + 1] = fmaxf(s1 + mb20, 0.f);
            if (eb + 2 < N_EDGES) out[eb + 2] = fmaxf(s2 + mb20, 0.f);
            if (eb + 3 < N_EDGES) out[eb + 3] = fmaxf(s3 + mb20, 0.f);
        }
    }
}

// ---------------------------------------------------------------- launch
extern "C" void kernel_launch(void* const* d_in, const int* in_sizes, int n_in,
                              void* d_out, int out_size, void* d_ws, size_t ws_size,
                              hipStream_t stream) {
    const float* x    = (const float*)d_in[0];
    const int*   ei   = (const int*)d_in[1];
    const float* w1   = (const float*)d_in[2];
    const float* as1  = (const float*)d_in[3];
    const float* ad1  = (const float*)d_in[4];
    const float* b1   = (const float*)d_in[5];
    const float* w2   = (const float*)d_in[6];
    const float* as2  = (const float*)d_in[7];
    const float* ad2  = (const float*)d_in[8];
    const float* b2   = (const float*)d_in[9];
    const float* mw1  = (const float*)d_in[10];
    const float* mb1  = (const float*)d_in[11];
    const float* mw2  = (const float*)d_in[12];
    const float* mb2  = (const float*)d_in[13];
    float* out = (float*)d_out;

    const int N = N_NODES;
    // byte-offset workspace layout; p1/h2/u/v 64B-aligned (offsets verified)
    char* base   = (char*)d_ws;
    int* deg     = (int*)(base);                      // N*4
    int* rowptr  = (int*)(base + 400000);             // N*4
    int* bstart  = (int*)(base + 800000);             // (NBUCK+1)*4 = 788 B
    int* bh      = (int*)(base + 1200000);            // BLKB*NBUCK*4 = 306,544 B
    int* csr_src = (int*)(base + 1602048);            // E*4
    float* p1    = (float*)(base + 8002048);          // 8N*4   (%64==0)
    float* a1d   = (float*)(base + 11202048);         // 4N*4
    __half* h2   = (__half*)(base + 12802048);        // 32N*2  (%64==0)
    int* binned  = (int*)(base + 19202048);           // E*4 (disjoint lifetime vs h2 region tail)
    float* a2s   = (float*)(base + 25602048);         // N*4
    float* a2d   = (float*)(base + 26002048);         // N*4
    __half* u    = (__half*)(base + 26402048);        // 32N*2  (%64==0)
    __half* v    = (__half*)(base + 32802048);        // 32N*2  (%64==0)
    float* qv    = (float*)(base + 39202048);         // 24

    const int nb = (N + 255) / 256;

    kA_hist<<<BLKB, 256, 0, stream>>>(ei, bh);
    kS1<<<NBUCK, 256, 0, stream>>>(bh, bstart);
    kS2<<<1, 256, 0, stream>>>(bstart);
    kB_bin<<<BLKB, 256, 0, stream>>>(ei, bh, bstart, binned);
    kC_sort<<<NBUCK, 256, 0, stream>>>(bstart, binned, deg, rowptr, csr_src);

    k_q<<<1, 32, 0, stream>>>(w1, as1, ad1, qv);
    k_node1<<<nb, 256, 0, stream>>>(x, qv, a1d, p1);

    k_gat1<<<G1_BLOCKS, 256, 0, stream>>>(rowptr, deg, csr_src, p1, w1, a1d,
                                          b1, w2, as2, ad2, h2, a2s, a2d);

    k_gat2<<<G2_BLOCKS, 256, 0, stream>>>(rowptr, deg, csr_src, h2, a2s, a2d, b2,
                                          mw1, mb1, u, v);

    k_mlp<<<MLP_BLOCKS, 256, 0, stream>>>(ei, u, v, mw2, mb2, out);
}

// Round 12
// 274.618 us; speedup vs baseline: 1.0455x; 1.0455x over previous
//
#include <hip/hip_runtime.h>
#include <hip/hip_fp16.h>
#include <math.h>

#define N_NODES 100000
#define N_EDGES 1600000
#define NEG_SLOPE 0.2f
#define EPS 1e-16f

// bucket sort geometry: 196 buckets of 512 nodes; 391 blocks x 4096 edges
#define NBUCK 196
#define CHUNK 4096
#define BLKB 391

typedef _Float16 hf2v __attribute__((ext_vector_type(2)));

__device__ __forceinline__ float lrelu(float v) { return v > 0.f ? v : NEG_SLOPE * v; }

// load 4 halfs -> float4 (single 8B load)
__device__ __forceinline__ float4 ld4h(const __half* p) {
    uint2 r = *(const uint2*)p;
    __half2 h0 = *reinterpret_cast<const __half2*>(&r.x);
    __half2 h1 = *reinterpret_cast<const __half2*>(&r.y);
    float2 f0 = __half22float2(h0), f1 = __half22float2(h1);
    return make_float4(f0.x, f0.y, f1.x, f1.y);
}

// load 8 halfs -> 8 floats (single 16B load)
__device__ __forceinline__ void ld8h(const __half* p, float* f) {
    uint4 r = *(const uint4*)p;
    __half2 h0 = *reinterpret_cast<const __half2*>(&r.x);
    __half2 h1 = *reinterpret_cast<const __half2*>(&r.y);
    __half2 h2 = *reinterpret_cast<const __half2*>(&r.z);
    __half2 h3 = *reinterpret_cast<const __half2*>(&r.w);
    float2 f0 = __half22float2(h0), f1 = __half22float2(h1);
    float2 f2 = __half22float2(h2), f3 = __half22float2(h3);
    f[0] = f0.x; f[1] = f0.y; f[2] = f1.x; f[3] = f1.y;
    f[4] = f2.x; f[5] = f2.y; f[6] = f3.x; f[7] = f3.y;
}

// ---------------------------------------------------------------- Pass A: per-block coarse histogram (LDS only)
__global__ void kA_hist(const int* __restrict__ ei, int* __restrict__ bh) {
    __shared__ int hist[NBUCK];
    int tid = threadIdx.x, b = blockIdx.x;
    if (tid < NBUCK) hist[tid] = 0;
    __syncthreads();
    int base = b * CHUNK;
    #pragma unroll
    for (int i = 0; i < CHUNK / 256; i++) {
        int e = base + i * 256 + tid;
        if (e < N_EDGES) {
            int dst = ei[N_EDGES + e];
            atomicAdd(&hist[dst >> 9], 1);
        }
    }
    __syncthreads();
    if (tid < NBUCK) bh[b * NBUCK + tid] = hist[tid];
}

// ---------------------------------------------------------------- S1: column scan of bh (one block per bucket)
__global__ void kS1(int* __restrict__ bh, int* __restrict__ bucketStart) {
    __shared__ int tsum[256];
    int k = blockIdx.x, t = threadIdx.x;
    int j0 = 2 * t, j1 = 2 * t + 1;
    int v0 = (j0 < BLKB) ? bh[j0 * NBUCK + k] : 0;
    int v1 = (j1 < BLKB) ? bh[j1 * NBUCK + k] : 0;
    int s = v0 + v1;
    tsum[t] = s;
    __syncthreads();
    for (int off = 1; off < 256; off <<= 1) {
        int tv = (t >= off) ? tsum[t - off] : 0;
        __syncthreads();
        tsum[t] += tv;
        __syncthreads();
    }
    int excl = tsum[t] - s;
    if (j0 < BLKB) bh[j0 * NBUCK + k] = excl;
    if (j1 < BLKB) bh[j1 * NBUCK + k] = excl + v0;
    if (t == 255) bucketStart[k] = tsum[255];   // column total (scanned by S2)
}

// ---------------------------------------------------------------- S2: scan bucket totals -> bucket starts (+ total at [NBUCK])
__global__ void kS2(int* __restrict__ bucketStart) {
    __shared__ int tmp[256];
    int t = threadIdx.x;
    int v = (t < NBUCK) ? bucketStart[t] : 0;
    tmp[t] = v;
    __syncthreads();
    for (int off = 1; off < 256; off <<= 1) {
        int tv = (t >= off) ? tmp[t - off] : 0;
        __syncthreads();
        tmp[t] += tv;
        __syncthreads();
    }
    if (t < NBUCK) bucketStart[t] = tmp[t] - v;
    if (t == NBUCK - 1) bucketStart[NBUCK] = tmp[t];
}

// ---------------------------------------------------------------- Pass B: bin edges by coarse bucket (LDS cursors, coalesced-run writes)
__global__ void kB_bin(const int* __restrict__ ei, const int* __restrict__ bh,
                       const int* __restrict__ bucketStart, int* __restrict__ binned) {
    __shared__ int cur[NBUCK];
    int tid = threadIdx.x, b = blockIdx.x;
    if (tid < NBUCK) cur[tid] = bucketStart[tid] + bh[b * NBUCK + tid];
    __syncthreads();
    int base = b * CHUNK;
    #pragma unroll
    for (int i = 0; i < CHUNK / 256; i++) {
        int e = base + i * 256 + tid;
        if (e < N_EDGES) {
            int src = ei[e], dst = ei[N_EDGES + e];
            int pos = atomicAdd(&cur[dst >> 9], 1);
            binned[pos] = src | ((dst & 511) << 17);
        }
    }
}

// ---------------------------------------------------------------- Pass C: per-bucket counting sort -> deg, rowptr, csr_src
__global__ void kC_sort(const int* __restrict__ bucketStart, const int* __restrict__ binned,
                        int* __restrict__ deg, int* __restrict__ rowptr,
                        int* __restrict__ csr_src) {
    __shared__ int cnt[512];
    __shared__ int pfx[512];
    __shared__ int bsum[256];
    int t = threadIdx.x, k = blockIdx.x;
    int s0 = bucketStart[k], s1 = bucketStart[k + 1];
    cnt[t] = 0; cnt[t + 256] = 0;
    __syncthreads();
    for (int i = s0 + t; i < s1; i += 256)
        atomicAdd(&cnt[binned[i] >> 17], 1);
    __syncthreads();
    int a0 = cnt[2 * t], a1 = cnt[2 * t + 1];
    int s = a0 + a1;
    bsum[t] = s;
    __syncthreads();
    for (int off = 1; off < 256; off <<= 1) {
        int tv = (t >= off) ? bsum[t - off] : 0;
        __syncthreads();
        bsum[t] += tv;
        __syncthreads();
    }
    int excl = bsum[t] - s;
    pfx[2 * t] = excl;
    pfx[2 * t + 1] = excl + a0;
    int nb0 = k << 9;
    int n0 = nb0 + 2 * t, n1 = nb0 + 2 * t + 1;
    if (n0 < N_NODES) { deg[n0] = a0; rowptr[n0] = s0 + excl; }
    if (n1 < N_NODES) { deg[n1] = a1; rowptr[n1] = s0 + excl + a0; }
    __syncthreads();
    for (int i = s0 + t; i < s1; i += 256) {
        int pkd = binned[i];
        int pos = s0 + atomicAdd(&pfx[pkd >> 17], 1);
        csr_src[pos] = pkd & 0x1FFFF;
    }
}

// ---------------------------------------------------------------- K-Q: qs[h] = W1_h^T a_src_h, qd[h] = W1_h^T a_dst_h  (24 floats)
__global__ void k_q(const float* __restrict__ w1, const float* __restrict__ as1,
                    const float* __restrict__ ad1, float* __restrict__ qv) {
    int t = threadIdx.x;
    if (t >= 24) return;
    int c = t % 3, h = (t / 3) % 4, side = t / 12;
    const float* att = side ? ad1 : as1;
    float acc = 0.f;
    for (int cc = 0; cc < 32; cc++)
        acc += att[h * 32 + cc] * w1[(h * 32 + cc) * 3 + c];
    qv[t] = acc;
}

// ---------------------------------------------------------------- K-NODE1: a1d = x.qd ; p1[n] = {a1s[4], x0,x1,x2,1} (32B row)
__global__ void k_node1(const float* __restrict__ x, const float* __restrict__ qv,
                        float* __restrict__ a1d, float* __restrict__ p1) {
    int n = blockIdx.x * blockDim.x + threadIdx.x;
    if (n >= N_NODES) return;
    float x0 = x[n * 3], x1 = x[n * 3 + 1], x2 = x[n * 3 + 2];
    float4 s, d;
    s.x = x0 * qv[0]  + x1 * qv[1]  + x2 * qv[2];
    s.y = x0 * qv[3]  + x1 * qv[4]  + x2 * qv[5];
    s.z = x0 * qv[6]  + x1 * qv[7]  + x2 * qv[8];
    s.w = x0 * qv[9]  + x1 * qv[10] + x2 * qv[11];
    d.x = x0 * qv[12] + x1 * qv[13] + x2 * qv[14];
    d.y = x0 * qv[15] + x1 * qv[16] + x2 * qv[17];
    d.z = x0 * qv[18] + x1 * qv[19] + x2 * qv[20];
    d.w = x0 * qv[21] + x1 * qv[22] + x2 * qv[23];
    ((float4*)a1d)[n] = d;
    ((float4*)p1)[n * 2]     = s;
    float4 xx; xx.x = x0; xx.y = x1; xx.z = x2; xx.w = 1.f;
    ((float4*)p1)[n * 2 + 1] = xx;
}

// ---------------------------------------------------------------- K-GAT1 v5: v2 skeleton + instruction-stream cuts
// Rounds 7/10/11 falsified structure levers (4/8/16-lane variants all 63-68us).
// v5 keeps the proven v2 structure (64 nodes/block, 4 lanes/node phase A,
// 16 nodes/wave phase B) and cuts the instruction stream:
//  - ELU via __expf(x)-1 (expm1f is libm: ~40+ divergent instrs, 128/node)
//  - phase-B dot in packed fp16: f1 staged as __half in LDS, w2 column as 32
//    half2 regs, 32x v_dot2_f32_f16 + 32 broadcast b32 reads (was 64 FMA + 64)
#define G1_BLOCKS ((N_NODES + 63) / 64)
__global__ void k_gat1(const int* __restrict__ rowptr, const int* __restrict__ deg,
                       const int* __restrict__ csr_src,
                       const float* __restrict__ p1, const float* __restrict__ w1,
                       const float* __restrict__ a1d,
                       const float* __restrict__ b1, const float* __restrict__ w2,
                       const float* __restrict__ as2, const float* __restrict__ ad2,
                       __half* __restrict__ h2, float* __restrict__ a2s, float* __restrict__ a2d) {
    __shared__ float sm[64][16];      // per-node: 4 heads x {s0,s1,s2,den}
    __shared__ __half f1h[4][128];    // per-wave f1 vector, fp16
    int tid = threadIdx.x;
    int wave = tid >> 6, lane = tid & 63;
    int o = lane & 31, half = lane >> 5;
    int k0 = half * 64;

    // ---- phase A: node = block*64 + wave*16 + (lane>>2); lane&3 = edge phase = head slot
    int nl = wave * 16 + (lane >> 2);
    int h  = lane & 3;
    int n  = blockIdx.x * 64 + nl;
    if (n < N_NODES) {
        float4 ad4 = ((const float4*)a1d)[n];          // broadcast across the quad
        float adv[4] = {ad4.x, ad4.y, ad4.z, ad4.w};
        int beg = rowptr[n], cnt = deg[n];
        float acc[4][4];                                // [head][{s0,s1,s2,den}]
        #pragma unroll
        for (int hh = 0; hh < 4; hh++)
            acc[hh][0] = acc[hh][1] = acc[hh][2] = acc[hh][3] = 0.f;
        int t = h;
        for (; t + 4 < cnt; t += 8) {                   // 2 edges/iter, 4 gathers in flight
            int i0 = csr_src[beg + t], i1 = csr_src[beg + t + 4];
            float4 A0 = ((const float4*)p1)[i0 * 2], X0 = ((const float4*)p1)[i0 * 2 + 1];
            float4 A1 = ((const float4*)p1)[i1 * 2], X1 = ((const float4*)p1)[i1 * 2 + 1];
            float a0v[4] = {A0.x, A0.y, A0.z, A0.w};
            float a1v[4] = {A1.x, A1.y, A1.z, A1.w};
            #pragma unroll
            for (int hh = 0; hh < 4; hh++) {
                float e0 = __expf(lrelu(a0v[hh] + adv[hh]));
                float e1 = __expf(lrelu(a1v[hh] + adv[hh]));
                acc[hh][0] += e0 * X0.x + e1 * X1.x;
                acc[hh][1] += e0 * X0.y + e1 * X1.y;
                acc[hh][2] += e0 * X0.z + e1 * X1.z;
                acc[hh][3] += e0 + e1;
            }
        }
        if (t < cnt) {                                  // at most 1 tail edge per lane
            int i0 = csr_src[beg + t];
            float4 A0 = ((const float4*)p1)[i0 * 2], X0 = ((const float4*)p1)[i0 * 2 + 1];
            float a0v[4] = {A0.x, A0.y, A0.z, A0.w};
            #pragma unroll
            for (int hh = 0; hh < 4; hh++) {
                float e0 = __expf(lrelu(a0v[hh] + adv[hh]));
                acc[hh][0] += e0 * X0.x;
                acc[hh][1] += e0 * X0.y;
                acc[hh][2] += e0 * X0.z;
                acc[hh][3] += e0;
            }
        }
        // 4-lane butterfly (quad is exec-uniform: same n) — every lane gets full sums
        #pragma unroll
        for (int hh = 0; hh < 4; hh++) {
            #pragma unroll
            for (int cc = 0; cc < 4; cc++) {
                float vv = acc[hh][cc];
                vv += __shfl_xor(vv, 1);
                vv += __shfl_xor(vv, 2);
                acc[hh][cc] = vv;
            }
        }
        float4 r;   // lane writes its own head's slice (static-index select, once per node)
        r.x = h == 0 ? acc[0][0] : h == 1 ? acc[1][0] : h == 2 ? acc[2][0] : acc[3][0];
        r.y = h == 0 ? acc[0][1] : h == 1 ? acc[1][1] : h == 2 ? acc[2][1] : acc[3][1];
        r.z = h == 0 ? acc[0][2] : h == 1 ? acc[1][2] : h == 2 ? acc[2][2] : acc[3][2];
        r.w = h == 0 ? acc[0][3] : h == 1 ? acc[1][3] : h == 2 ? acc[2][3] : acc[3][3];
        *(float4*)&sm[nl][h * 4] = r;
    }
    // same-wave LDS write->read below: no barrier needed

    // per-lane w2 column packed to half2 AFTER phase A (low gather-loop VGPR pressure)
    hf2v w2h[32];
    {
        const float4* wp = (const float4*)(w2 + o * 128 + k0);
        #pragma unroll
        for (int q = 0; q < 16; q++) {
            float4 t4 = wp[q];
            __half2 p0 = __floats2half2_rn(t4.x, t4.y);
            __half2 p1h = __floats2half2_rn(t4.z, t4.w);
            w2h[2 * q]     = *reinterpret_cast<hf2v*>(&p0);
            w2h[2 * q + 1] = *reinterpret_cast<hf2v*>(&p1h);
        }
    }

    // ---- phase B: wave processes its own 16 nodes
    int j = lane, j2 = lane + 64;
    int h0 = j >> 5;
    float wa0 = w1[j * 3], wa1 = w1[j * 3 + 1], wa2 = w1[j * 3 + 2];
    float wb0 = w1[j2 * 3], wb1 = w1[j2 * 3 + 1], wb2 = w1[j2 * 3 + 2];
    float b1j = b1[j], b1j2 = b1[j2];
    float as2o = as2[o], ad2o = ad2[o];
    const unsigned int* fp = (const unsigned int*)&f1h[wave][k0];

    #pragma unroll 1
    for (int i = 0; i < 16; i++) {
        int n2 = blockIdx.x * 64 + wave * 16 + i;
        if (n2 >= N_NODES) break;
        const float* S = sm[wave * 16 + i];
        float v0 = (wa0 * S[h0 * 4] + wa1 * S[h0 * 4 + 1] + wa2 * S[h0 * 4 + 2])
                   / (S[h0 * 4 + 3] + EPS) + b1j;
        float v1 = (wb0 * S[(2 + h0) * 4] + wb1 * S[(2 + h0) * 4 + 1] + wb2 * S[(2 + h0) * 4 + 2])
                   / (S[(2 + h0) * 4 + 3] + EPS) + b1j2;
        float e0 = v0 > 0.f ? v0 : __expf(v0) - 1.f;   // ELU via fast exp (no libm expm1f)
        float e1 = v1 > 0.f ? v1 : __expf(v1) - 1.f;
        f1h[wave][j]  = __float2half(e0);
        f1h[wave][j2] = __float2half(e1);
        float acc = 0.f;
        #pragma unroll
        for (int t = 0; t < 32; t++) {
            unsigned int fw = fp[t];                   // broadcast b32: 2 halfs
            hf2v fv = *reinterpret_cast<hf2v*>(&fw);
#if __has_builtin(__builtin_amdgcn_fdot2)
            acc = __builtin_amdgcn_fdot2(fv, w2h[t], acc, false);
#else
            acc += (float)fv[0] * (float)w2h[t][0] + (float)fv[1] * (float)w2h[t][1];
#endif
        }
        acc += __shfl_down(acc, 32);
        if (half == 0) {
            h2[n2 * 32 + o] = __float2half(acc);   // fp16 row (64 B, coalesced)
            float ps = acc * as2o, pd = acc * ad2o;
            #pragma unroll
            for (int off = 16; off; off >>= 1) {
                ps += __shfl_xor(ps, off);
                pd += __shfl_xor(pd, off);
            }
            if (o == 0) { a2s[n2] = ps; a2d[n2] = pd; }
        }
    }
}

// ---------------------------------------------------------------- K-GAT2 v5: 16 lanes/node, 4 nodes/wave (4x miss chains)
#define G2_BLOCKS ((N_NODES + 15) / 16)
__global__ void k_gat2(const int* __restrict__ rowptr, const int* __restrict__ deg,
                       const int* __restrict__ csr_src,
                       const __half* __restrict__ h2, const float* __restrict__ a2s,
                       const float* __restrict__ a2d, const float* __restrict__ b2,
                       const float* __restrict__ mw1, const float* __restrict__ mb1,
                       __half* __restrict__ u, __half* __restrict__ v) {
    __shared__ float Ws2[2][32 * 36];    // [half][c*36+k]; row start 144B (16B-aligned)
    __shared__ int2  pk[4][64];          // per-wave staged (idx, e-bits), 16 slots/group
    __shared__ float4 hfs[4][4][8];      // [wave][group][8 quads] = hf vector (32 floats)
    int tid = threadIdx.x;
    for (int i = tid; i < 2048; i += 256) {
        int c = i >> 6, col = i & 63;
        Ws2[col >> 5][c * 36 + (col & 31)] = mw1[i];
    }
    __syncthreads();
    int lane = tid & 63, w = tid >> 6;
    int nl = lane >> 4, sl = lane & 15;          // group (node) / sub-lane
    int eg2 = sl >> 2, qq = sl & 3;              // edge slot / 16-B chunk
    int n = blockIdx.x * 16 + w * 4 + nl;        // one node per group, no stride loop
    float4 b2a = ((const float4*)b2)[qq * 2];    // channels qq*8 .. qq*8+3
    float4 b2b = ((const float4*)b2)[qq * 2 + 1];// channels qq*8+4 .. qq*8+7

    int beg = 0, cnt = 0;
    float ad = 0.f;
    if (n < N_NODES) { beg = rowptr[n]; cnt = deg[n]; ad = a2d[n]; }

    float acc[8] = {0.f, 0.f, 0.f, 0.f, 0.f, 0.f, 0.f, 0.f};
    float den = 0.f;
    int pkbase = (nl << 4);
    for (int b16 = 0; b16 < cnt; b16 += 16) {    // group-divergent, exec-masked
        int li = b16 + sl;
        int idx = (li < cnt) ? csr_src[beg + li] : 0;
        float e = 0.f;
        if (li < cnt) e = __expf(lrelu(a2s[idx] + ad));
        den += e;
        pk[w][pkbase + sl] = make_int2(idx, __float_as_int(e)); // same-wave stage
        #pragma unroll
        for (int p = 0; p < 4; p++) {            // fixed 4 steps: 4 rows in flight/group
            int2 pe = pk[w][pkbase + p * 4 + eg2];
            float g[8];
            ld8h(h2 + pe.x * 32 + qq * 8, g);    // 16-B gather (8 halfs)
            float ee = __int_as_float(pe.y);     // 0 for pads
            acc[0] += ee * g[0]; acc[1] += ee * g[1];
            acc[2] += ee * g[2]; acc[3] += ee * g[3];
            acc[4] += ee * g[4]; acc[5] += ee * g[5];
            acc[6] += ee * g[6]; acc[7] += ee * g[7];
        }
    }
    // reduce across the 4 edge slots (within 16-lane group)
    #pragma unroll
    for (int j = 0; j < 8; j++) {
        float vv = acc[j];
        vv += __shfl_xor(vv, 4);
        vv += __shfl_xor(vv, 8);
        acc[j] = vv;
    }
    den += __shfl_xor(den, 1); den += __shfl_xor(den, 2);
    den += __shfl_xor(den, 4); den += __shfl_xor(den, 8);
    float inv = 1.f / (den + EPS);
    if (sl < 4) {                                // sl<4 => eg2=0, qq=sl
        float4 ha, hb;
        ha.x = acc[0] * inv + b2a.x; ha.y = acc[1] * inv + b2a.y;
        ha.z = acc[2] * inv + b2a.z; ha.w = acc[3] * inv + b2a.w;
        hb.x = acc[4] * inv + b2b.x; hb.y = acc[5] * inv + b2b.y;
        hb.z = acc[6] * inv + b2b.z; hb.w = acc[7] * inv + b2b.w;
        hfs[w][nl][qq * 2]     = ha;             // same-wave stage
        hfs[w][nl][qq * 2 + 1] = hb;
    }
    // epilogue: 16 lanes per node, 4 output channels per lane
    if (n < N_NODES) {
        int half_o = sl >> 3, c4 = (sl & 7) * 4;
        __half* outp = half_o ? v : u;
        float r0 = half_o ? 0.f : mb1[c4 + 0];
        float r1 = half_o ? 0.f : mb1[c4 + 1];
        float r2 = half_o ? 0.f : mb1[c4 + 2];
        float r3 = half_o ? 0.f : mb1[c4 + 3];
        const float* Wb = &Ws2[half_o][0];
        #pragma unroll
        for (int q = 0; q < 8; q++) {
            float4 hq = hfs[w][nl][q];           // broadcast within group
            float4 W0 = *(const float4*)&Wb[(c4 + 0) * 36 + q * 4];
            float4 W1 = *(const float4*)&Wb[(c4 + 1) * 36 + q * 4];
            float4 W2 = *(const float4*)&Wb[(c4 + 2) * 36 + q * 4];
            float4 W3 = *(const float4*)&Wb[(c4 + 3) * 36 + q * 4];
            r0 += W0.x * hq.x + W0.y * hq.y + W0.z * hq.z + W0.w * hq.w;
            r1 += W1.x * hq.x + W1.y * hq.y + W1.z * hq.z + W1.w * hq.w;
            r2 += W2.x * hq.x + W2.y * hq.y + W2.z * hq.z + W2.w * hq.w;
            r3 += W3.x * hq.x + W3.y * hq.y + W3.z * hq.z + W3.w * hq.w;
        }
        __half2 p0, p1;
        p0.x = __float2half(r0); p0.y = __float2half(r1);
        p1.x = __float2half(r2); p1.y = __float2half(r3);
        uint2 st;
        st.x = *reinterpret_cast<unsigned int*>(&p0);
        st.y = *reinterpret_cast<unsigned int*>(&p1);
        *reinterpret_cast<uint2*>(outp + n * 32 + c4) = st;  // 8-B aligned store
    }
}

// ---------------------------------------------------------------- K-MLP: 8 lanes/edge, 4 edges/iter, fp16 u/v rows (1 line each)
#define MLP_BLOCKS 4096
__global__ void k_mlp(const int* __restrict__ ei, const __half* __restrict__ u,
                      const __half* __restrict__ v, const float* __restrict__ mw2,
                      const float* __restrict__ mb2, float* __restrict__ out) {
    int tid = threadIdx.x;
    int q = tid & 7;
    float4 w2q = ((const float4*)mw2)[q];
    float mb20 = mb2[0];
    int g = blockIdx.x * 32 + (tid >> 3);
    const int stride = MLP_BLOCKS * 32 * 4;
    for (int e = g * 4; e < N_EDGES; e += stride) {
        int eb = e;
        int e1 = (eb + 1 < N_EDGES) ? eb + 1 : eb;
        int e2 = (eb + 2 < N_EDGES) ? eb + 2 : eb;
        int e3 = (eb + 3 < N_EDGES) ? eb + 3 : eb;
        int sa = ei[eb], da = ei[N_EDGES + eb];
        int sb = ei[e1], db = ei[N_EDGES + e1];
        int sc = ei[e2], dc = ei[N_EDGES + e2];
        int sd = ei[e3], dd = ei[N_EDGES + e3];
        float4 ua = ld4h(u + sa * 32 + q * 4);
        float4 va = ld4h(v + da * 32 + q * 4);
        float4 ub = ld4h(u + sb * 32 + q * 4);
        float4 vb = ld4h(v + db * 32 + q * 4);
        float4 uc = ld4h(u + sc * 32 + q * 4);
        float4 vc = ld4h(v + dc * 32 + q * 4);
        float4 ud = ld4h(u + sd * 32 + q * 4);
        float4 vd = ld4h(v + dd * 32 + q * 4);
        float s0 = fmaxf(ua.x + va.x, 0.f) * w2q.x + fmaxf(ua.y + va.y, 0.f) * w2q.y
                 + fmaxf(ua.z + va.z, 0.f) * w2q.z + fmaxf(ua.w + va.w, 0.f) * w2q.w;
        float s1 = fmaxf(ub.x + vb.x, 0.f) * w2q.x + fmaxf(ub.y + vb.y, 0.f) * w2q.y
                 + fmaxf(ub.z + vb.z, 0.f) * w2q.z + fmaxf(ub.w + vb.w, 0.f) * w2q.w;
        float s2 = fmaxf(uc.x + vc.x, 0.f) * w2q.x + fmaxf(uc.y + vc.y, 0.f) * w2q.y
                 + fmaxf(uc.z + vc.z, 0.f) * w2q.z + fmaxf(uc.w + vc.w, 0.f) * w2q.w;
        float s3 = fmaxf(ud.x + vd.x, 0.f) * w2q.x + fmaxf(ud.y + vd.y, 0.f) * w2q.y
                 + fmaxf(ud.z + vd.z, 0.f) * w2q.z + fmaxf(ud.w + vd.w, 0.f) * w2q.w;
        s0 += __shfl_xor(s0, 1, 8); s0 += __shfl_xor(s0, 2, 8); s0 += __shfl_xor(s0, 4, 8);
        s1 += __shfl_xor(s1, 1, 8); s1 += __shfl_xor(s1, 2, 8); s1 += __shfl_xor(s1, 4, 8);
        s2 += __shfl_xor(s2, 1, 8); s2 += __shfl_xor(s2, 2, 8); s2 += __shfl_xor(s2, 4, 8);
        s3 += __shfl_xor(s3, 1, 8); s3 += __shfl_xor(s3, 2, 8); s3 += __shfl_xor(s3, 4, 8);
        if (q == 0) {
            out[eb] = fmaxf(s0 + mb20, 0.f);
            if (eb + 1 < N_EDGES) out[eb + 1] = fmaxf(s1 + mb20, 0.f);
            if (eb + 2 < N_EDGES) out[eb + 2] = fmaxf(s2 + mb20, 0.f);
            if (eb + 3 < N_EDGES) out[eb + 3] = fmaxf(s3 + mb20, 0.f);
        }
    }
}

// ---------------------------------------------------------------- launch
extern "C" void kernel_launch(void* const* d_in, const int* in_sizes, int n_in,
                              void* d_out, int out_size, void* d_ws, size_t ws_size,
                              hipStream_t stream) {
    const float* x    = (const float*)d_in[0];
    const int*   ei   = (const int*)d_in[1];
    const float* w1   = (const float*)d_in[2];
    const float* as1  = (const float*)d_in[3];
    const float* ad1  = (const float*)d_in[4];
    const float* b1   = (const float*)d_in[5];
    const float* w2   = (const float*)d_in[6];
    const float* as2  = (const float*)d_in[7];
    const float* ad2  = (const float*)d_in[8];
    const float* b2   = (const float*)d_in[9];
    const float* mw1  = (const float*)d_in[10];
    const float* mb1  = (const float*)d_in[11];
    const float* mw2  = (const float*)d_in[12];
    const float* mb2  = (const float*)d_in[13];
    float* out = (float*)d_out;

    const int N = N_NODES;
    // byte-offset workspace layout; p1/h2/u/v 64B-aligned (offsets verified)
    char* base   = (char*)d_ws;
    int* deg     = (int*)(base);                      // N*4
    int* rowptr  = (int*)(base + 400000);             // N*4
    int* bstart  = (int*)(base + 800000);             // (NBUCK+1)*4 = 788 B
    int* bh      = (int*)(base + 1200000);            // BLKB*NBUCK*4 = 306,544 B
    int* csr_src = (int*)(base + 1602048);            // E*4
    float* p1    = (float*)(base + 8002048);          // 8N*4   (%64==0)
    float* a1d   = (float*)(base + 11202048);         // 4N*4
    __half* h2   = (__half*)(base + 12802048);        // 32N*2  (%64==0)
    int* binned  = (int*)(base + 19202048);           // E*4 (disjoint lifetime vs h2 region tail)
    float* a2s   = (float*)(base + 25602048);         // N*4
    float* a2d   = (float*)(base + 26002048);         // N*4
    __half* u    = (__half*)(base + 26402048);        // 32N*2  (%64==0)
    __half* v    = (__half*)(base + 32802048);        // 32N*2  (%64==0)
    float* qv    = (float*)(base + 39202048);         // 24

    const int nb = (N + 255) / 256;

    kA_hist<<<BLKB, 256, 0, stream>>>(ei, bh);
    kS1<<<NBUCK, 256, 0, stream>>>(bh, bstart);
    kS2<<<1, 256, 0, stream>>>(bstart);
    kB_bin<<<BLKB, 256, 0, stream>>>(ei, bh, bstart, binned);
    kC_sort<<<NBUCK, 256, 0, stream>>>(bstart, binned, deg, rowptr, csr_src);

    k_q<<<1, 32, 0, stream>>>(w1, as1, ad1, qv);
    k_node1<<<nb, 256, 0, stream>>>(x, qv, a1d, p1);

    k_gat1<<<G1_BLOCKS, 256, 0, stream>>>(rowptr, deg, csr_src, p1, w1, a1d,
                                          b1, w2, as2, ad2, h2, a2s, a2d);

    k_gat2<<<G2_BLOCKS, 256, 0, stream>>>(rowptr, deg, csr_src, h2, a2s, a2d, b2,
                                          mw1, mb1, u, v);

    k_mlp<<<MLP_BLOCKS, 256, 0, stream>>>(ei, u, v, mw2, mb2, out);
}

// Round 13
// 260.558 us; speedup vs baseline: 1.1019x; 1.0540x over previous
//
#include <hip/hip_runtime.h>
#include <hip/hip_fp16.h>
#include <math.h>

#define N_NODES 100000
#define N_EDGES 1600000
#define NEG_SLOPE 0.2f
#define EPS 1e-16f

// bucket sort geometry: 196 buckets of 512 nodes; 391 blocks x 4096 edges
#define NBUCK 196
#define CHUNK 4096
#define BLKB 391

typedef _Float16 f16x8 __attribute__((ext_vector_type(8)));
typedef float f32x4 __attribute__((ext_vector_type(4)));

__device__ __forceinline__ float lrelu(float v) { return v > 0.f ? v : NEG_SLOPE * v; }

// load 4 halfs -> float4 (single 8B load)
__device__ __forceinline__ float4 ld4h(const __half* p) {
    uint2 r = *(const uint2*)p;
    __half2 h0 = *reinterpret_cast<const __half2*>(&r.x);
    __half2 h1 = *reinterpret_cast<const __half2*>(&r.y);
    float2 f0 = __half22float2(h0), f1 = __half22float2(h1);
    return make_float4(f0.x, f0.y, f1.x, f1.y);
}

// load 8 halfs -> 8 floats (single 16B load)
__device__ __forceinline__ void ld8h(const __half* p, float* f) {
    uint4 r = *(const uint4*)p;
    __half2 h0 = *reinterpret_cast<const __half2*>(&r.x);
    __half2 h1 = *reinterpret_cast<const __half2*>(&r.y);
    __half2 h2 = *reinterpret_cast<const __half2*>(&r.z);
    __half2 h3 = *reinterpret_cast<const __half2*>(&r.w);
    float2 f0 = __half22float2(h0), f1 = __half22float2(h1);
    float2 f2 = __half22float2(h2), f3 = __half22float2(h3);
    f[0] = f0.x; f[1] = f0.y; f[2] = f1.x; f[3] = f1.y;
    f[4] = f2.x; f[5] = f2.y; f[6] = f3.x; f[7] = f3.y;
}

// ---------------------------------------------------------------- Pass A: per-block coarse histogram (LDS only)
__global__ void kA_hist(const int* __restrict__ ei, int* __restrict__ bh) {
    __shared__ int hist[NBUCK];
    int tid = threadIdx.x, b = blockIdx.x;
    if (tid < NBUCK) hist[tid] = 0;
    __syncthreads();
    int base = b * CHUNK;
    #pragma unroll
    for (int i = 0; i < CHUNK / 256; i++) {
        int e = base + i * 256 + tid;
        if (e < N_EDGES) {
            int dst = ei[N_EDGES + e];
            atomicAdd(&hist[dst >> 9], 1);
        }
    }
    __syncthreads();
    if (tid < NBUCK) bh[b * NBUCK + tid] = hist[tid];
}

// ---------------------------------------------------------------- S1: column scan of bh (one block per bucket)
__global__ void kS1(int* __restrict__ bh, int* __restrict__ bucketStart) {
    __shared__ int tsum[256];
    int k = blockIdx.x, t = threadIdx.x;
    int j0 = 2 * t, j1 = 2 * t + 1;
    int v0 = (j0 < BLKB) ? bh[j0 * NBUCK + k] : 0;
    int v1 = (j1 < BLKB) ? bh[j1 * NBUCK + k] : 0;
    int s = v0 + v1;
    tsum[t] = s;
    __syncthreads();
    for (int off = 1; off < 256; off <<= 1) {
        int tv = (t >= off) ? tsum[t - off] : 0;
        __syncthreads();
        tsum[t] += tv;
        __syncthreads();
    }
    int excl = tsum[t] - s;
    if (j0 < BLKB) bh[j0 * NBUCK + k] = excl;
    if (j1 < BLKB) bh[j1 * NBUCK + k] = excl + v0;
    if (t == 255) bucketStart[k] = tsum[255];   // column total (scanned by S2)
}

// ---------------------------------------------------------------- S2: scan bucket totals -> bucket starts (+ total at [NBUCK])
__global__ void kS2(int* __restrict__ bucketStart) {
    __shared__ int tmp[256];
    int t = threadIdx.x;
    int v = (t < NBUCK) ? bucketStart[t] : 0;
    tmp[t] = v;
    __syncthreads();
    for (int off = 1; off < 256; off <<= 1) {
        int tv = (t >= off) ? tmp[t - off] : 0;
        __syncthreads();
        tmp[t] += tv;
        __syncthreads();
    }
    if (t < NBUCK) bucketStart[t] = tmp[t] - v;
    if (t == NBUCK - 1) bucketStart[NBUCK] = tmp[t];
}

// ---------------------------------------------------------------- Pass B: bin edges by coarse bucket (LDS cursors, coalesced-run writes)
__global__ void kB_bin(const int* __restrict__ ei, const int* __restrict__ bh,
                       const int* __restrict__ bucketStart, int* __restrict__ binned) {
    __shared__ int cur[NBUCK];
    int tid = threadIdx.x, b = blockIdx.x;
    if (tid < NBUCK) cur[tid] = bucketStart[tid] + bh[b * NBUCK + tid];
    __syncthreads();
    int base = b * CHUNK;
    #pragma unroll
    for (int i = 0; i < CHUNK / 256; i++) {
        int e = base + i * 256 + tid;
        if (e < N_EDGES) {
            int src = ei[e], dst = ei[N_EDGES + e];
            int pos = atomicAdd(&cur[dst >> 9], 1);
            binned[pos] = src | ((dst & 511) << 17);
        }
    }
}

// ---------------------------------------------------------------- Pass C: per-bucket counting sort -> deg, rowptr, csr_src
__global__ void kC_sort(const int* __restrict__ bucketStart, const int* __restrict__ binned,
                        int* __restrict__ deg, int* __restrict__ rowptr,
                        int* __restrict__ csr_src) {
    __shared__ int cnt[512];
    __shared__ int pfx[512];
    __shared__ int bsum[256];
    int t = threadIdx.x, k = blockIdx.x;
    int s0 = bucketStart[k], s1 = bucketStart[k + 1];
    cnt[t] = 0; cnt[t + 256] = 0;
    __syncthreads();
    for (int i = s0 + t; i < s1; i += 256)
        atomicAdd(&cnt[binned[i] >> 17], 1);
    __syncthreads();
    int a0 = cnt[2 * t], a1 = cnt[2 * t + 1];
    int s = a0 + a1;
    bsum[t] = s;
    __syncthreads();
    for (int off = 1; off < 256; off <<= 1) {
        int tv = (t >= off) ? bsum[t - off] : 0;
        __syncthreads();
        bsum[t] += tv;
        __syncthreads();
    }
    int excl = bsum[t] - s;
    pfx[2 * t] = excl;
    pfx[2 * t + 1] = excl + a0;
    int nb0 = k << 9;
    int n0 = nb0 + 2 * t, n1 = nb0 + 2 * t + 1;
    if (n0 < N_NODES) { deg[n0] = a0; rowptr[n0] = s0 + excl; }
    if (n1 < N_NODES) { deg[n1] = a1; rowptr[n1] = s0 + excl + a0; }
    __syncthreads();
    for (int i = s0 + t; i < s1; i += 256) {
        int pkd = binned[i];
        int pos = s0 + atomicAdd(&pfx[pkd >> 17], 1);
        csr_src[pos] = pkd & 0x1FFFF;
    }
}

// ---------------------------------------------------------------- K-Q: qs[h] = W1_h^T a_src_h, qd[h] = W1_h^T a_dst_h  (24 floats)
__global__ void k_q(const float* __restrict__ w1, const float* __restrict__ as1,
                    const float* __restrict__ ad1, float* __restrict__ qv) {
    int t = threadIdx.x;
    if (t >= 24) return;
    int c = t % 3, h = (t / 3) % 4, side = t / 12;
    const float* att = side ? ad1 : as1;
    float acc = 0.f;
    for (int cc = 0; cc < 32; cc++)
        acc += att[h * 32 + cc] * w1[(h * 32 + cc) * 3 + c];
    qv[t] = acc;
}

// ---------------------------------------------------------------- K-NODE1: a1d = x.qd ; p1[n] = {a1s[4], x0,x1,x2,1} (32B row)
__global__ void k_node1(const float* __restrict__ x, const float* __restrict__ qv,
                        float* __restrict__ a1d, float* __restrict__ p1) {
    int n = blockIdx.x * blockDim.x + threadIdx.x;
    if (n >= N_NODES) return;
    float x0 = x[n * 3], x1 = x[n * 3 + 1], x2 = x[n * 3 + 2];
    float4 s, d;
    s.x = x0 * qv[0]  + x1 * qv[1]  + x2 * qv[2];
    s.y = x0 * qv[3]  + x1 * qv[4]  + x2 * qv[5];
    s.z = x0 * qv[6]  + x1 * qv[7]  + x2 * qv[8];
    s.w = x0 * qv[9]  + x1 * qv[10] + x2 * qv[11];
    d.x = x0 * qv[12] + x1 * qv[13] + x2 * qv[14];
    d.y = x0 * qv[15] + x1 * qv[16] + x2 * qv[17];
    d.z = x0 * qv[18] + x1 * qv[19] + x2 * qv[20];
    d.w = x0 * qv[21] + x1 * qv[22] + x2 * qv[23];
    ((float4*)a1d)[n] = d;
    ((float4*)p1)[n * 2]     = s;
    float4 xx; xx.x = x0; xx.y = x1; xx.z = x2; xx.w = 1.f;
    ((float4*)p1)[n * 2 + 1] = xx;
}

// ---------------------------------------------------------------- K-GAT1 v6: phase B as per-wave 16x32x128 MFMA GEMM
// v5 analysis: phase B's scalar dot (16 nodes x 32 ds_read + 32 fdot) was
// ~8x phase A's instruction stream. v6 stages f1 (fp16) in LDS [16][136]
// (pad -> 2-way banks) and computes h2 = F1 @ w2^T with 8x
// v_mfma_f32_16x16x32_f16 + 4 ds_read_b128 A-frags per wave.
// Fragment maps: A: i=lane%16, k=(lane/16)*8+j. B: n=lane%16, k=(lane/16)*8+j.
// D: col=lane&15, row=(lane>>4)*4+reg (guide m89).
#define G1_BLOCKS ((N_NODES + 63) / 64)
__global__ void k_gat1(const int* __restrict__ rowptr, const int* __restrict__ deg,
                       const int* __restrict__ csr_src,
                       const float* __restrict__ p1, const float* __restrict__ w1,
                       const float* __restrict__ a1d,
                       const float* __restrict__ b1, const float* __restrict__ w2,
                       const float* __restrict__ as2, const float* __restrict__ ad2,
                       __half* __restrict__ h2, float* __restrict__ a2s, float* __restrict__ a2d) {
    __shared__ float sm[64][16];                        // per-node: 4 heads x {s0,s1,s2,den}
    __shared__ __align__(16) __half F1h[4][16][136];    // per-wave f1, fp16, padded rows
    int tid = threadIdx.x;
    int wave = tid >> 6, lane = tid & 63;

    // ---- phase A: node = block*64 + wave*16 + (lane>>2); lane&3 = edge phase = head slot
    int nl = wave * 16 + (lane >> 2);
    int h  = lane & 3;
    int n  = blockIdx.x * 64 + nl;
    if (n < N_NODES) {
        float4 ad4 = ((const float4*)a1d)[n];          // broadcast across the quad
        float adv[4] = {ad4.x, ad4.y, ad4.z, ad4.w};
        int beg = rowptr[n], cnt = deg[n];
        float acc[4][4];                                // [head][{s0,s1,s2,den}]
        #pragma unroll
        for (int hh = 0; hh < 4; hh++)
            acc[hh][0] = acc[hh][1] = acc[hh][2] = acc[hh][3] = 0.f;
        int t = h;
        for (; t + 4 < cnt; t += 8) {                   // 2 edges/iter, 4 gathers in flight
            int i0 = csr_src[beg + t], i1 = csr_src[beg + t + 4];
            float4 A0 = ((const float4*)p1)[i0 * 2], X0 = ((const float4*)p1)[i0 * 2 + 1];
            float4 A1 = ((const float4*)p1)[i1 * 2], X1 = ((const float4*)p1)[i1 * 2 + 1];
            float a0v[4] = {A0.x, A0.y, A0.z, A0.w};
            float a1v[4] = {A1.x, A1.y, A1.z, A1.w};
            #pragma unroll
            for (int hh = 0; hh < 4; hh++) {
                float e0 = __expf(lrelu(a0v[hh] + adv[hh]));
                float e1 = __expf(lrelu(a1v[hh] + adv[hh]));
                acc[hh][0] += e0 * X0.x + e1 * X1.x;
                acc[hh][1] += e0 * X0.y + e1 * X1.y;
                acc[hh][2] += e0 * X0.z + e1 * X1.z;
                acc[hh][3] += e0 + e1;
            }
        }
        if (t < cnt) {                                  // at most 1 tail edge per lane
            int i0 = csr_src[beg + t];
            float4 A0 = ((const float4*)p1)[i0 * 2], X0 = ((const float4*)p1)[i0 * 2 + 1];
            float a0v[4] = {A0.x, A0.y, A0.z, A0.w};
            #pragma unroll
            for (int hh = 0; hh < 4; hh++) {
                float e0 = __expf(lrelu(a0v[hh] + adv[hh]));
                acc[hh][0] += e0 * X0.x;
                acc[hh][1] += e0 * X0.y;
                acc[hh][2] += e0 * X0.z;
                acc[hh][3] += e0;
            }
        }
        // 4-lane butterfly (quad is exec-uniform: same n) — every lane gets full sums
        #pragma unroll
        for (int hh = 0; hh < 4; hh++) {
            #pragma unroll
            for (int cc = 0; cc < 4; cc++) {
                float vv = acc[hh][cc];
                vv += __shfl_xor(vv, 1);
                vv += __shfl_xor(vv, 2);
                acc[hh][cc] = vv;
            }
        }
        float4 r;   // lane writes its own head's slice (static-index select, once per node)
        r.x = h == 0 ? acc[0][0] : h == 1 ? acc[1][0] : h == 2 ? acc[2][0] : acc[3][0];
        r.y = h == 0 ? acc[0][1] : h == 1 ? acc[1][1] : h == 2 ? acc[2][1] : acc[3][1];
        r.z = h == 0 ? acc[0][2] : h == 1 ? acc[1][2] : h == 2 ? acc[2][2] : acc[3][2];
        r.w = h == 0 ? acc[0][3] : h == 1 ? acc[1][3] : h == 2 ? acc[2][3] : acc[3][3];
        *(float4*)&sm[nl][h * 4] = r;
    }
    // same-wave LDS write->read below: no barrier needed

    // ---- B-fragments: Bf[tile][ks], lane elem e = w2[tile*16+(lane&15)][ks*32+(lane>>4)*8+e]
    f16x8 Bf[2][4];
    {
        int bn = lane & 15, bg = lane >> 4;
        #pragma unroll
        for (int tile = 0; tile < 2; tile++) {
            const float* wrow = w2 + (tile * 16 + bn) * 128 + bg * 8;
            #pragma unroll
            for (int ks = 0; ks < 4; ks++) {
                const float4* wp = (const float4*)(wrow + ks * 32);
                float4 u0 = wp[0], u1 = wp[1];
                f16x8 bf;
                bf[0] = (_Float16)u0.x; bf[1] = (_Float16)u0.y;
                bf[2] = (_Float16)u0.z; bf[3] = (_Float16)u0.w;
                bf[4] = (_Float16)u1.x; bf[5] = (_Float16)u1.y;
                bf[6] = (_Float16)u1.z; bf[7] = (_Float16)u1.w;
                Bf[tile][ks] = bf;
            }
        }
    }

    // ---- phase B step 1: f1 (fp16) for the wave's 16 nodes -> F1h
    int j = lane, j2 = lane + 64;
    int h0 = j >> 5;
    float wa0 = w1[j * 3], wa1 = w1[j * 3 + 1], wa2 = w1[j * 3 + 2];
    float wb0 = w1[j2 * 3], wb1 = w1[j2 * 3 + 1], wb2 = w1[j2 * 3 + 2];
    float b1j = b1[j], b1j2 = b1[j2];

    #pragma unroll 1
    for (int i = 0; i < 16; i++) {
        int n2 = blockIdx.x * 64 + wave * 16 + i;
        if (n2 >= N_NODES) break;
        const float* S = sm[wave * 16 + i];
        float v0 = (wa0 * S[h0 * 4] + wa1 * S[h0 * 4 + 1] + wa2 * S[h0 * 4 + 2])
                   / (S[h0 * 4 + 3] + EPS) + b1j;
        float v1 = (wb0 * S[(2 + h0) * 4] + wb1 * S[(2 + h0) * 4 + 1] + wb2 * S[(2 + h0) * 4 + 2])
                   / (S[(2 + h0) * 4 + 3] + EPS) + b1j2;
        float e0 = v0 > 0.f ? v0 : __expf(v0) - 1.f;   // ELU via fast exp
        float e1 = v1 > 0.f ? v1 : __expf(v1) - 1.f;
        F1h[wave][i][j]  = __float2half(e0);
        F1h[wave][i][j2] = __float2half(e1);
    }

    // ---- phase B step 2: 8 MFMA (2 col-tiles x 4 K-steps); A-frag via ds_read_b128
    f32x4 d0 = {0.f, 0.f, 0.f, 0.f}, d1 = {0.f, 0.f, 0.f, 0.f};
    {
        int am = lane & 15, ag = lane >> 4;
        const __half* Arow = &F1h[wave][am][0];
        #pragma unroll
        for (int ks = 0; ks < 4; ks++) {
            f16x8 af = *(const f16x8*)&Arow[ks * 32 + ag * 8];   // 16B-aligned
            d0 = __builtin_amdgcn_mfma_f32_16x16x32_f16(af, Bf[0][ks], d0, 0, 0, 0);
            d1 = __builtin_amdgcn_mfma_f32_16x16x32_f16(af, Bf[1][ks], d1, 0, 0, 0);
        }
    }

    // ---- epilogue: D col = lane&15 (channel), row = (lane>>4)*4+r (node)
    {
        int ch = lane & 15, rg = lane >> 4;
        float as2a = as2[ch], as2b = as2[ch + 16];
        float ad2a = ad2[ch], ad2b = ad2[ch + 16];
        #pragma unroll
        for (int r = 0; r < 4; r++) {
            int n2 = blockIdx.x * 64 + wave * 16 + rg * 4 + r;
            float va = d0[r], vb = d1[r];
            if (n2 < N_NODES) {
                h2[n2 * 32 + ch]      = __float2half(va);
                h2[n2 * 32 + ch + 16] = __float2half(vb);
            }
            float ps = va * as2a + vb * as2b;
            float pd = va * ad2a + vb * ad2b;
            ps += __shfl_xor(ps, 1); ps += __shfl_xor(ps, 2);
            ps += __shfl_xor(ps, 4); ps += __shfl_xor(ps, 8);
            pd += __shfl_xor(pd, 1); pd += __shfl_xor(pd, 2);
            pd += __shfl_xor(pd, 4); pd += __shfl_xor(pd, 8);
            if (ch == 0 && n2 < N_NODES) { a2s[n2] = ps; a2d[n2] = pd; }
        }
    }
}

// ---------------------------------------------------------------- K-GAT2 v5: 16 lanes/node, 4 nodes/wave (4x miss chains)
#define G2_BLOCKS ((N_NODES + 15) / 16)
__global__ void k_gat2(const int* __restrict__ rowptr, const int* __restrict__ deg,
                       const int* __restrict__ csr_src,
                       const __half* __restrict__ h2, const float* __restrict__ a2s,
                       const float* __restrict__ a2d, const float* __restrict__ b2,
                       const float* __restrict__ mw1, const float* __restrict__ mb1,
                       __half* __restrict__ u, __half* __restrict__ v) {
    __shared__ float Ws2[2][32 * 36];    // [half][c*36+k]; row start 144B (16B-aligned)
    __shared__ int2  pk[4][64];          // per-wave staged (idx, e-bits), 16 slots/group
    __shared__ float4 hfs[4][4][8];      // [wave][group][8 quads] = hf vector (32 floats)
    int tid = threadIdx.x;
    for (int i = tid; i < 2048; i += 256) {
        int c = i >> 6, col = i & 63;
        Ws2[col >> 5][c * 36 + (col & 31)] = mw1[i];
    }
    __syncthreads();
    int lane = tid & 63, w = tid >> 6;
    int nl = lane >> 4, sl = lane & 15;          // group (node) / sub-lane
    int eg2 = sl >> 2, qq = sl & 3;              // edge slot / 16-B chunk
    int n = blockIdx.x * 16 + w * 4 + nl;        // one node per group, no stride loop
    float4 b2a = ((const float4*)b2)[qq * 2];    // channels qq*8 .. qq*8+3
    float4 b2b = ((const float4*)b2)[qq * 2 + 1];// channels qq*8+4 .. qq*8+7

    int beg = 0, cnt = 0;
    float ad = 0.f;
    if (n < N_NODES) { beg = rowptr[n]; cnt = deg[n]; ad = a2d[n]; }

    float acc[8] = {0.f, 0.f, 0.f, 0.f, 0.f, 0.f, 0.f, 0.f};
    float den = 0.f;
    int pkbase = (nl << 4);
    for (int b16 = 0; b16 < cnt; b16 += 16) {    // group-divergent, exec-masked
        int li = b16 + sl;
        int idx = (li < cnt) ? csr_src[beg + li] : 0;
        float e = 0.f;
        if (li < cnt) e = __expf(lrelu(a2s[idx] + ad));
        den += e;
        pk[w][pkbase + sl] = make_int2(idx, __float_as_int(e)); // same-wave stage
        #pragma unroll
        for (int p = 0; p < 4; p++) {            // fixed 4 steps: 4 rows in flight/group
            int2 pe = pk[w][pkbase + p * 4 + eg2];
            float g[8];
            ld8h(h2 + pe.x * 32 + qq * 8, g);    // 16-B gather (8 halfs)
            float ee = __int_as_float(pe.y);     // 0 for pads
            acc[0] += ee * g[0]; acc[1] += ee * g[1];
            acc[2] += ee * g[2]; acc[3] += ee * g[3];
            acc[4] += ee * g[4]; acc[5] += ee * g[5];
            acc[6] += ee * g[6]; acc[7] += ee * g[7];
        }
    }
    // reduce across the 4 edge slots (within 16-lane group)
    #pragma unroll
    for (int j = 0; j < 8; j++) {
        float vv = acc[j];
        vv += __shfl_xor(vv, 4);
        vv += __shfl_xor(vv, 8);
        acc[j] = vv;
    }
    den += __shfl_xor(den, 1); den += __shfl_xor(den, 2);
    den += __shfl_xor(den, 4); den += __shfl_xor(den, 8);
    float inv = 1.f / (den + EPS);
    if (sl < 4) {                                // sl<4 => eg2=0, qq=sl
        float4 ha, hb;
        ha.x = acc[0] * inv + b2a.x; ha.y = acc[1] * inv + b2a.y;
        ha.z = acc[2] * inv + b2a.z; ha.w = acc[3] * inv + b2a.w;
        hb.x = acc[4] * inv + b2b.x; hb.y = acc[5] * inv + b2b.y;
        hb.z = acc[6] * inv + b2b.z; hb.w = acc[7] * inv + b2b.w;
        hfs[w][nl][qq * 2]     = ha;             // same-wave stage
        hfs[w][nl][qq * 2 + 1] = hb;
    }
    // epilogue: 16 lanes per node, 4 output channels per lane
    if (n < N_NODES) {
        int half_o = sl >> 3, c4 = (sl & 7) * 4;
        __half* outp = half_o ? v : u;
        float r0 = half_o ? 0.f : mb1[c4 + 0];
        float r1 = half_o ? 0.f : mb1[c4 + 1];
        float r2 = half_o ? 0.f : mb1[c4 + 2];
        float r3 = half_o ? 0.f : mb1[c4 + 3];
        const float* Wb = &Ws2[half_o][0];
        #pragma unroll
        for (int q = 0; q < 8; q++) {
            float4 hq = hfs[w][nl][q];           // broadcast within group
            float4 W0 = *(const float4*)&Wb[(c4 + 0) * 36 + q * 4];
            float4 W1 = *(const float4*)&Wb[(c4 + 1) * 36 + q * 4];
            float4 W2 = *(const float4*)&Wb[(c4 + 2) * 36 + q * 4];
            float4 W3 = *(const float4*)&Wb[(c4 + 3) * 36 + q * 4];
            r0 += W0.x * hq.x + W0.y * hq.y + W0.z * hq.z + W0.w * hq.w;
            r1 += W1.x * hq.x + W1.y * hq.y + W1.z * hq.z + W1.w * hq.w;
            r2 += W2.x * hq.x + W2.y * hq.y + W2.z * hq.z + W2.w * hq.w;
            r3 += W3.x * hq.x + W3.y * hq.y + W3.z * hq.z + W3.w * hq.w;
        }
        __half2 p0, p1;
        p0.x = __float2half(r0); p0.y = __float2half(r1);
        p1.x = __float2half(r2); p1.y = __float2half(r3);
        uint2 st;
        st.x = *reinterpret_cast<unsigned int*>(&p0);
        st.y = *reinterpret_cast<unsigned int*>(&p1);
        *reinterpret_cast<uint2*>(outp + n * 32 + c4) = st;  // 8-B aligned store
    }
}

// ---------------------------------------------------------------- K-MLP: 8 lanes/edge, 4 edges/iter, fp16 u/v rows (1 line each)
#define MLP_BLOCKS 4096
__global__ void k_mlp(const int* __restrict__ ei, const __half* __restrict__ u,
                      const __half* __restrict__ v, const float* __restrict__ mw2,
                      const float* __restrict__ mb2, float* __restrict__ out) {
    int tid = threadIdx.x;
    int q = tid & 7;
    float4 w2q = ((const float4*)mw2)[q];
    float mb20 = mb2[0];
    int g = blockIdx.x * 32 + (tid >> 3);
    const int stride = MLP_BLOCKS * 32 * 4;
    for (int e = g * 4; e < N_EDGES; e += stride) {
        int eb = e;
        int e1 = (eb + 1 < N_EDGES) ? eb + 1 : eb;
        int e2 = (eb + 2 < N_EDGES) ? eb + 2 : eb;
        int e3 = (eb + 3 < N_EDGES) ? eb + 3 : eb;
        int sa = ei[eb], da = ei[N_EDGES + eb];
        int sb = ei[e1], db = ei[N_EDGES + e1];
        int sc = ei[e2], dc = ei[N_EDGES + e2];
        int sd = ei[e3], dd = ei[N_EDGES + e3];
        float4 ua = ld4h(u + sa * 32 + q * 4);
        float4 va = ld4h(v + da * 32 + q * 4);
        float4 ub = ld4h(u + sb * 32 + q * 4);
        float4 vb = ld4h(v + db * 32 + q * 4);
        float4 uc = ld4h(u + sc * 32 + q * 4);
        float4 vc = ld4h(v + dc * 32 + q * 4);
        float4 ud = ld4h(u + sd * 32 + q * 4);
        float4 vd = ld4h(v + dd * 32 + q * 4);
        float s0 = fmaxf(ua.x + va.x, 0.f) * w2q.x + fmaxf(ua.y + va.y, 0.f) * w2q.y
                 + fmaxf(ua.z + va.z, 0.f) * w2q.z + fmaxf(ua.w + va.w, 0.f) * w2q.w;
        float s1 = fmaxf(ub.x + vb.x, 0.f) * w2q.x + fmaxf(ub.y + vb.y, 0.f) * w2q.y
                 + fmaxf(ub.z + vb.z, 0.f) * w2q.z + fmaxf(ub.w + vb.w, 0.f) * w2q.w;
        float s2 = fmaxf(uc.x + vc.x, 0.f) * w2q.x + fmaxf(uc.y + vc.y, 0.f) * w2q.y
                 + fmaxf(uc.z + vc.z, 0.f) * w2q.z + fmaxf(uc.w + vc.w, 0.f) * w2q.w;
        float s3 = fmaxf(ud.x + vd.x, 0.f) * w2q.x + fmaxf(ud.y + vd.y, 0.f) * w2q.y
                 + fmaxf(ud.z + vd.z, 0.f) * w2q.z + fmaxf(ud.w + vd.w, 0.f) * w2q.w;
        s0 += __shfl_xor(s0, 1, 8); s0 += __shfl_xor(s0, 2, 8); s0 += __shfl_xor(s0, 4, 8);
        s1 += __shfl_xor(s1, 1, 8); s1 += __shfl_xor(s1, 2, 8); s1 += __shfl_xor(s1, 4, 8);
        s2 += __shfl_xor(s2, 1, 8); s2 += __shfl_xor(s2, 2, 8); s2 += __shfl_xor(s2, 4, 8);
        s3 += __shfl_xor(s3, 1, 8); s3 += __shfl_xor(s3, 2, 8); s3 += __shfl_xor(s3, 4, 8);
        if (q == 0) {
            out[eb] = fmaxf(s0 + mb20, 0.f);
            if (eb + 1 < N_EDGES) out[eb + 1] = fmaxf(s1 + mb20, 0.f);
            if (eb + 2 < N_EDGES) out[eb + 2] = fmaxf(s2 + mb20, 0.f);
            if (eb + 3 < N_EDGES) out[eb + 3] = fmaxf(s3 + mb20, 0.f);
        }
    }
}

// ---------------------------------------------------------------- launch
extern "C" void kernel_launch(void* const* d_in, const int* in_sizes, int n_in,
                              void* d_out, int out_size, void* d_ws, size_t ws_size,
                              hipStream_t stream) {
    const float* x    = (const float*)d_in[0];
    const int*   ei   = (const int*)d_in[1];
    const float* w1   = (const float*)d_in[2];
    const float* as1  = (const float*)d_in[3];
    const float* ad1  = (const float*)d_in[4];
    const float* b1   = (const float*)d_in[5];
    const float* w2   = (const float*)d_in[6];
    const float* as2  = (const float*)d_in[7];
    const float* ad2  = (const float*)d_in[8];
    const float* b2   = (const float*)d_in[9];
    const float* mw1  = (const float*)d_in[10];
    const float* mb1  = (const float*)d_in[11];
    const float* mw2  = (const float*)d_in[12];
    const float* mb2  = (const float*)d_in[13];
    float* out = (float*)d_out;

    const int N = N_NODES;
    // byte-offset workspace layout; p1/h2/u/v 64B-aligned (offsets verified)
    char* base   = (char*)d_ws;
    int* deg     = (int*)(base);                      // N*4
    int* rowptr  = (int*)(base + 400000);             // N*4
    int* bstart  = (int*)(base + 800000);             // (NBUCK+1)*4 = 788 B
    int* bh      = (int*)(base + 1200000);            // BLKB*NBUCK*4 = 306,544 B
    int* csr_src = (int*)(base + 1602048);            // E*4
    float* p1    = (float*)(base + 8002048);          // 8N*4   (%64==0)
    float* a1d   = (float*)(base + 11202048);         // 4N*4
    __half* h2   = (__half*)(base + 12802048);        // 32N*2  (%64==0)
    int* binned  = (int*)(base + 19202048);           // E*4 (disjoint lifetime vs h2 region tail)
    float* a2s   = (float*)(base + 25602048);         // N*4
    float* a2d   = (float*)(base + 26002048);         // N*4
    __half* u    = (__half*)(base + 26402048);        // 32N*2  (%64==0)
    __half* v    = (__half*)(base + 32802048);        // 32N*2  (%64==0)
    float* qv    = (float*)(base + 39202048);         // 24

    const int nb = (N + 255) / 256;

    kA_hist<<<BLKB, 256, 0, stream>>>(ei, bh);
    kS1<<<NBUCK, 256, 0, stream>>>(bh, bstart);
    kS2<<<1, 256, 0, stream>>>(bstart);
    kB_bin<<<BLKB, 256, 0, stream>>>(ei, bh, bstart, binned);
    kC_sort<<<NBUCK, 256, 0, stream>>>(bstart, binned, deg, rowptr, csr_src);

    k_q<<<1, 32, 0, stream>>>(w1, as1, ad1, qv);
    k_node1<<<nb, 256, 0, stream>>>(x, qv, a1d, p1);

    k_gat1<<<G1_BLOCKS, 256, 0, stream>>>(rowptr, deg, csr_src, p1, w1, a1d,
                                          b1, w2, as2, ad2, h2, a2s, a2d);

    k_gat2<<<G2_BLOCKS, 256, 0, stream>>>(rowptr, deg, csr_src, h2, a2s, a2d, b2,
                                          mw1, mb1, u, v);

    k_mlp<<<MLP_BLOCKS, 256, 0, stream>>>(ei, u, v, mw2, mb2, out);
}

// Round 14
// 250.663 us; speedup vs baseline: 1.1454x; 1.0395x over previous
//
#include <hip/hip_runtime.h>
#include <hip/hip_fp16.h>
#include <math.h>

#define N_NODES 100000
#define N_EDGES 1600000
#define NEG_SLOPE 0.2f
#define EPS 1e-16f

// bucket sort geometry: 196 buckets of 512 nodes; 391 blocks x 4096 edges
#define NBUCK 196
#define CHUNK 4096
#define BLKB 391

typedef _Float16 f16x8 __attribute__((ext_vector_type(8)));
typedef float f32x4 __attribute__((ext_vector_type(4)));

__device__ __forceinline__ float lrelu(float v) { return v > 0.f ? v : NEG_SLOPE * v; }

// load 4 halfs -> float4 (single 8B load)
__device__ __forceinline__ float4 ld4h(const __half* p) {
    uint2 r = *(const uint2*)p;
    __half2 h0 = *reinterpret_cast<const __half2*>(&r.x);
    __half2 h1 = *reinterpret_cast<const __half2*>(&r.y);
    float2 f0 = __half22float2(h0), f1 = __half22float2(h1);
    return make_float4(f0.x, f0.y, f1.x, f1.y);
}

// load 8 halfs -> 8 floats (single 16B load)
__device__ __forceinline__ void ld8h(const __half* p, float* f) {
    uint4 r = *(const uint4*)p;
    __half2 h0 = *reinterpret_cast<const __half2*>(&r.x);
    __half2 h1 = *reinterpret_cast<const __half2*>(&r.y);
    __half2 h2 = *reinterpret_cast<const __half2*>(&r.z);
    __half2 h3 = *reinterpret_cast<const __half2*>(&r.w);
    float2 f0 = __half22float2(h0), f1 = __half22float2(h1);
    float2 f2 = __half22float2(h2), f3 = __half22float2(h3);
    f[0] = f0.x; f[1] = f0.y; f[2] = f1.x; f[3] = f1.y;
    f[4] = f2.x; f[5] = f2.y; f[6] = f3.x; f[7] = f3.y;
}

// ---------------------------------------------------------------- Pass A: per-block coarse histogram (LDS only)
__global__ void kA_hist(const int* __restrict__ ei, int* __restrict__ bh) {
    __shared__ int hist[NBUCK];
    int tid = threadIdx.x, b = blockIdx.x;
    if (tid < NBUCK) hist[tid] = 0;
    __syncthreads();
    int base = b * CHUNK;
    #pragma unroll
    for (int i = 0; i < CHUNK / 256; i++) {
        int e = base + i * 256 + tid;
        if (e < N_EDGES) {
            int dst = ei[N_EDGES + e];
            atomicAdd(&hist[dst >> 9], 1);
        }
    }
    __syncthreads();
    if (tid < NBUCK) bh[b * NBUCK + tid] = hist[tid];
}

// ---------------------------------------------------------------- S1: column scan of bh (one block per bucket)
__global__ void kS1(int* __restrict__ bh, int* __restrict__ bucketStart) {
    __shared__ int tsum[256];
    int k = blockIdx.x, t = threadIdx.x;
    int j0 = 2 * t, j1 = 2 * t + 1;
    int v0 = (j0 < BLKB) ? bh[j0 * NBUCK + k] : 0;
    int v1 = (j1 < BLKB) ? bh[j1 * NBUCK + k] : 0;
    int s = v0 + v1;
    tsum[t] = s;
    __syncthreads();
    for (int off = 1; off < 256; off <<= 1) {
        int tv = (t >= off) ? tsum[t - off] : 0;
        __syncthreads();
        tsum[t] += tv;
        __syncthreads();
    }
    int excl = tsum[t] - s;
    if (j0 < BLKB) bh[j0 * NBUCK + k] = excl;
    if (j1 < BLKB) bh[j1 * NBUCK + k] = excl + v0;
    if (t == 255) bucketStart[k] = tsum[255];   // column total (scanned by S2)
}

// ---------------------------------------------------------------- S2: scan bucket totals -> bucket starts (+ total at [NBUCK])
__global__ void kS2(int* __restrict__ bucketStart) {
    __shared__ int tmp[256];
    int t = threadIdx.x;
    int v = (t < NBUCK) ? bucketStart[t] : 0;
    tmp[t] = v;
    __syncthreads();
    for (int off = 1; off < 256; off <<= 1) {
        int tv = (t >= off) ? tmp[t - off] : 0;
        __syncthreads();
        tmp[t] += tv;
        __syncthreads();
    }
    if (t < NBUCK) bucketStart[t] = tmp[t] - v;
    if (t == NBUCK - 1) bucketStart[NBUCK] = tmp[t];
}

// ---------------------------------------------------------------- Pass B: bin edges by coarse bucket (LDS cursors, coalesced-run writes)
__global__ void kB_bin(const int* __restrict__ ei, const int* __restrict__ bh,
                       const int* __restrict__ bucketStart, int* __restrict__ binned) {
    __shared__ int cur[NBUCK];
    int tid = threadIdx.x, b = blockIdx.x;
    if (tid < NBUCK) cur[tid] = bucketStart[tid] + bh[b * NBUCK + tid];
    __syncthreads();
    int base = b * CHUNK;
    #pragma unroll
    for (int i = 0; i < CHUNK / 256; i++) {
        int e = base + i * 256 + tid;
        if (e < N_EDGES) {
            int src = ei[e], dst = ei[N_EDGES + e];
            int pos = atomicAdd(&cur[dst >> 9], 1);
            binned[pos] = src | ((dst & 511) << 17);
        }
    }
}

// ---------------------------------------------------------------- Pass C: per-bucket counting sort -> deg, rowptr, csr_src
__global__ void kC_sort(const int* __restrict__ bucketStart, const int* __restrict__ binned,
                        int* __restrict__ deg, int* __restrict__ rowptr,
                        int* __restrict__ csr_src) {
    __shared__ int cnt[512];
    __shared__ int pfx[512];
    __shared__ int bsum[256];
    int t = threadIdx.x, k = blockIdx.x;
    int s0 = bucketStart[k], s1 = bucketStart[k + 1];
    cnt[t] = 0; cnt[t + 256] = 0;
    __syncthreads();
    for (int i = s0 + t; i < s1; i += 256)
        atomicAdd(&cnt[binned[i] >> 17], 1);
    __syncthreads();
    int a0 = cnt[2 * t], a1 = cnt[2 * t + 1];
    int s = a0 + a1;
    bsum[t] = s;
    __syncthreads();
    for (int off = 1; off < 256; off <<= 1) {
        int tv = (t >= off) ? bsum[t - off] : 0;
        __syncthreads();
        bsum[t] += tv;
        __syncthreads();
    }
    int excl = bsum[t] - s;
    pfx[2 * t] = excl;
    pfx[2 * t + 1] = excl + a0;
    int nb0 = k << 9;
    int n0 = nb0 + 2 * t, n1 = nb0 + 2 * t + 1;
    if (n0 < N_NODES) { deg[n0] = a0; rowptr[n0] = s0 + excl; }
    if (n1 < N_NODES) { deg[n1] = a1; rowptr[n1] = s0 + excl + a0; }
    __syncthreads();
    for (int i = s0 + t; i < s1; i += 256) {
        int pkd = binned[i];
        int pos = s0 + atomicAdd(&pfx[pkd >> 17], 1);
        csr_src[pos] = pkd & 0x1FFFF;
    }
}

// ---------------------------------------------------------------- K-Q: qs[h] = W1_h^T a_src_h, qd[h] = W1_h^T a_dst_h  (24 floats)
__global__ void k_q(const float* __restrict__ w1, const float* __restrict__ as1,
                    const float* __restrict__ ad1, float* __restrict__ qv) {
    int t = threadIdx.x;
    if (t >= 24) return;
    int c = t % 3, h = (t / 3) % 4, side = t / 12;
    const float* att = side ? ad1 : as1;
    float acc = 0.f;
    for (int cc = 0; cc < 32; cc++)
        acc += att[h * 32 + cc] * w1[(h * 32 + cc) * 3 + c];
    qv[t] = acc;
}

// ---------------------------------------------------------------- K-NODE1: a1d = x.qd ; p1[n] = {a1s[4], x0,x1,x2,1} (32B row)
__global__ void k_node1(const float* __restrict__ x, const float* __restrict__ qv,
                        float* __restrict__ a1d, float* __restrict__ p1) {
    int n = blockIdx.x * blockDim.x + threadIdx.x;
    if (n >= N_NODES) return;
    float x0 = x[n * 3], x1 = x[n * 3 + 1], x2 = x[n * 3 + 2];
    float4 s, d;
    s.x = x0 * qv[0]  + x1 * qv[1]  + x2 * qv[2];
    s.y = x0 * qv[3]  + x1 * qv[4]  + x2 * qv[5];
    s.z = x0 * qv[6]  + x1 * qv[7]  + x2 * qv[8];
    s.w = x0 * qv[9]  + x1 * qv[10] + x2 * qv[11];
    d.x = x0 * qv[12] + x1 * qv[13] + x2 * qv[14];
    d.y = x0 * qv[15] + x1 * qv[16] + x2 * qv[17];
    d.z = x0 * qv[18] + x1 * qv[19] + x2 * qv[20];
    d.w = x0 * qv[21] + x1 * qv[22] + x2 * qv[23];
    ((float4*)a1d)[n] = d;
    ((float4*)p1)[n * 2]     = s;
    float4 xx; xx.x = x0; xx.y = x1; xx.z = x2; xx.w = 1.f;
    ((float4*)p1)[n * 2 + 1] = xx;
}

// ---------------------------------------------------------------- K-GAT1 v6: phase B as per-wave 16x32x128 MFMA GEMM
#define G1_BLOCKS ((N_NODES + 63) / 64)
__global__ void k_gat1(const int* __restrict__ rowptr, const int* __restrict__ deg,
                       const int* __restrict__ csr_src,
                       const float* __restrict__ p1, const float* __restrict__ w1,
                       const float* __restrict__ a1d,
                       const float* __restrict__ b1, const float* __restrict__ w2,
                       const float* __restrict__ as2, const float* __restrict__ ad2,
                       __half* __restrict__ h2, float* __restrict__ a2s, float* __restrict__ a2d) {
    __shared__ float sm[64][16];                        // per-node: 4 heads x {s0,s1,s2,den}
    __shared__ __align__(16) __half F1h[4][16][136];    // per-wave f1, fp16, padded rows
    int tid = threadIdx.x;
    int wave = tid >> 6, lane = tid & 63;

    // ---- phase A: node = block*64 + wave*16 + (lane>>2); lane&3 = edge phase = head slot
    int nl = wave * 16 + (lane >> 2);
    int h  = lane & 3;
    int n  = blockIdx.x * 64 + nl;
    if (n < N_NODES) {
        float4 ad4 = ((const float4*)a1d)[n];          // broadcast across the quad
        float adv[4] = {ad4.x, ad4.y, ad4.z, ad4.w};
        int beg = rowptr[n], cnt = deg[n];
        float acc[4][4];                                // [head][{s0,s1,s2,den}]
        #pragma unroll
        for (int hh = 0; hh < 4; hh++)
            acc[hh][0] = acc[hh][1] = acc[hh][2] = acc[hh][3] = 0.f;
        int t = h;
        for (; t + 4 < cnt; t += 8) {                   // 2 edges/iter, 4 gathers in flight
            int i0 = csr_src[beg + t], i1 = csr_src[beg + t + 4];
            float4 A0 = ((const float4*)p1)[i0 * 2], X0 = ((const float4*)p1)[i0 * 2 + 1];
            float4 A1 = ((const float4*)p1)[i1 * 2], X1 = ((const float4*)p1)[i1 * 2 + 1];
            float a0v[4] = {A0.x, A0.y, A0.z, A0.w};
            float a1v[4] = {A1.x, A1.y, A1.z, A1.w};
            #pragma unroll
            for (int hh = 0; hh < 4; hh++) {
                float e0 = __expf(lrelu(a0v[hh] + adv[hh]));
                float e1 = __expf(lrelu(a1v[hh] + adv[hh]));
                acc[hh][0] += e0 * X0.x + e1 * X1.x;
                acc[hh][1] += e0 * X0.y + e1 * X1.y;
                acc[hh][2] += e0 * X0.z + e1 * X1.z;
                acc[hh][3] += e0 + e1;
            }
        }
        if (t < cnt) {                                  // at most 1 tail edge per lane
            int i0 = csr_src[beg + t];
            float4 A0 = ((const float4*)p1)[i0 * 2], X0 = ((const float4*)p1)[i0 * 2 + 1];
            float a0v[4] = {A0.x, A0.y, A0.z, A0.w};
            #pragma unroll
            for (int hh = 0; hh < 4; hh++) {
                float e0 = __expf(lrelu(a0v[hh] + adv[hh]));
                acc[hh][0] += e0 * X0.x;
                acc[hh][1] += e0 * X0.y;
                acc[hh][2] += e0 * X0.z;
                acc[hh][3] += e0;
            }
        }
        // 4-lane butterfly (quad is exec-uniform: same n) — every lane gets full sums
        #pragma unroll
        for (int hh = 0; hh < 4; hh++) {
            #pragma unroll
            for (int cc = 0; cc < 4; cc++) {
                float vv = acc[hh][cc];
                vv += __shfl_xor(vv, 1);
                vv += __shfl_xor(vv, 2);
                acc[hh][cc] = vv;
            }
        }
        float4 r;   // lane writes its own head's slice (static-index select, once per node)
        r.x = h == 0 ? acc[0][0] : h == 1 ? acc[1][0] : h == 2 ? acc[2][0] : acc[3][0];
        r.y = h == 0 ? acc[0][1] : h == 1 ? acc[1][1] : h == 2 ? acc[2][1] : acc[3][1];
        r.z = h == 0 ? acc[0][2] : h == 1 ? acc[1][2] : h == 2 ? acc[2][2] : acc[3][2];
        r.w = h == 0 ? acc[0][3] : h == 1 ? acc[1][3] : h == 2 ? acc[2][3] : acc[3][3];
        *(float4*)&sm[nl][h * 4] = r;
    }
    // same-wave LDS write->read below: no barrier needed

    // ---- B-fragments: Bf[tile][ks], lane elem e = w2[tile*16+(lane&15)][ks*32+(lane>>4)*8+e]
    f16x8 Bf[2][4];
    {
        int bn = lane & 15, bg = lane >> 4;
        #pragma unroll
        for (int tile = 0; tile < 2; tile++) {
            const float* wrow = w2 + (tile * 16 + bn) * 128 + bg * 8;
            #pragma unroll
            for (int ks = 0; ks < 4; ks++) {
                const float4* wp = (const float4*)(wrow + ks * 32);
                float4 u0 = wp[0], u1 = wp[1];
                f16x8 bf;
                bf[0] = (_Float16)u0.x; bf[1] = (_Float16)u0.y;
                bf[2] = (_Float16)u0.z; bf[3] = (_Float16)u0.w;
                bf[4] = (_Float16)u1.x; bf[5] = (_Float16)u1.y;
                bf[6] = (_Float16)u1.z; bf[7] = (_Float16)u1.w;
                Bf[tile][ks] = bf;
            }
        }
    }

    // ---- phase B step 1: f1 (fp16) for the wave's 16 nodes -> F1h
    int j = lane, j2 = lane + 64;
    int h0 = j >> 5;
    float wa0 = w1[j * 3], wa1 = w1[j * 3 + 1], wa2 = w1[j * 3 + 2];
    float wb0 = w1[j2 * 3], wb1 = w1[j2 * 3 + 1], wb2 = w1[j2 * 3 + 2];
    float b1j = b1[j], b1j2 = b1[j2];

    #pragma unroll 1
    for (int i = 0; i < 16; i++) {
        int n2 = blockIdx.x * 64 + wave * 16 + i;
        if (n2 >= N_NODES) break;
        const float* S = sm[wave * 16 + i];
        float v0 = (wa0 * S[h0 * 4] + wa1 * S[h0 * 4 + 1] + wa2 * S[h0 * 4 + 2])
                   / (S[h0 * 4 + 3] + EPS) + b1j;
        float v1 = (wb0 * S[(2 + h0) * 4] + wb1 * S[(2 + h0) * 4 + 1] + wb2 * S[(2 + h0) * 4 + 2])
                   / (S[(2 + h0) * 4 + 3] + EPS) + b1j2;
        float e0 = v0 > 0.f ? v0 : __expf(v0) - 1.f;   // ELU via fast exp
        float e1 = v1 > 0.f ? v1 : __expf(v1) - 1.f;
        F1h[wave][i][j]  = __float2half(e0);
        F1h[wave][i][j2] = __float2half(e1);
    }

    // ---- phase B step 2: 8 MFMA (2 col-tiles x 4 K-steps); A-frag via ds_read_b128
    f32x4 d0 = {0.f, 0.f, 0.f, 0.f}, d1 = {0.f, 0.f, 0.f, 0.f};
    {
        int am = lane & 15, ag = lane >> 4;
        const __half* Arow = &F1h[wave][am][0];
        #pragma unroll
        for (int ks = 0; ks < 4; ks++) {
            f16x8 af = *(const f16x8*)&Arow[ks * 32 + ag * 8];   // 16B-aligned
            d0 = __builtin_amdgcn_mfma_f32_16x16x32_f16(af, Bf[0][ks], d0, 0, 0, 0);
            d1 = __builtin_amdgcn_mfma_f32_16x16x32_f16(af, Bf[1][ks], d1, 0, 0, 0);
        }
    }

    // ---- epilogue: D col = lane&15 (channel), row = (lane>>4)*4+r (node)
    {
        int ch = lane & 15, rg = lane >> 4;
        float as2a = as2[ch], as2b = as2[ch + 16];
        float ad2a = ad2[ch], ad2b = ad2[ch + 16];
        #pragma unroll
        for (int r = 0; r < 4; r++) {
            int n2 = blockIdx.x * 64 + wave * 16 + rg * 4 + r;
            float va = d0[r], vb = d1[r];
            if (n2 < N_NODES) {
                h2[n2 * 32 + ch]      = __float2half(va);
                h2[n2 * 32 + ch + 16] = __float2half(vb);
            }
            float ps = va * as2a + vb * as2b;
            float pd = va * ad2a + vb * ad2b;
            ps += __shfl_xor(ps, 1); ps += __shfl_xor(ps, 2);
            ps += __shfl_xor(ps, 4); ps += __shfl_xor(ps, 8);
            pd += __shfl_xor(pd, 1); pd += __shfl_xor(pd, 2);
            pd += __shfl_xor(pd, 4); pd += __shfl_xor(pd, 8);
            if (ch == 0 && n2 < N_NODES) { a2s[n2] = ps; a2d[n2] = pd; }
        }
    }
}

// ---------------------------------------------------------------- K-GAT2 v6: bank-conflict-free LDS layouts
// Round-12 counters: SQ_LDS_BANK_CONFLICT = 9.6M/dispatch. Fixes:
//  pk int2[4][64] (group stride 32 dwords = 0 mod 32, 4-way)  -> planar
//    pidx/pe with group stride 17 ints (<=2-way, free)
//  hfs float4 stride 32 dwords (4-way) -> hfv floats, row stride 36 (4*nl bank
//    offset per group, broadcast-free)
//  Ws2 stride-36 rows stepped by 4 (2 bank-sets for 16 rows, up to 8-way) ->
//    TRANSPOSED WT[k][slot] stride 68: at each k the 16 lanes read consecutive
//    slots (banks 4*sl, 2-way max), hf[k] is a group-broadcast scalar.
#define G2_BLOCKS ((N_NODES + 15) / 16)
__global__ void k_gat2(const int* __restrict__ rowptr, const int* __restrict__ deg,
                       const int* __restrict__ csr_src,
                       const __half* __restrict__ h2, const float* __restrict__ a2s,
                       const float* __restrict__ a2d, const float* __restrict__ b2,
                       const float* __restrict__ mw1, const float* __restrict__ mb1,
                       __half* __restrict__ u, __half* __restrict__ v) {
    __shared__ __align__(16) float WT[32][68];  // WT[k][slot]: slot s = half*32+c -> mw1[c][half*32+k]
    __shared__ int   pidx[4][68];               // per-wave staged idx, group stride 17
    __shared__ float pe[4][68];                 // per-wave staged e,   group stride 17
    __shared__ float hfv[4][144];               // per-wave hf, group row stride 36
    int tid = threadIdx.x;
    for (int i = tid; i < 2048; i += 256) {
        int s = i >> 5, k = i & 31;
        WT[k][s] = mw1[(s & 31) * 64 + (s >> 5) * 32 + k];
    }
    __syncthreads();
    int lane = tid & 63, w = tid >> 6;
    int nl = lane >> 4, sl = lane & 15;          // group (node) / sub-lane
    int eg2 = sl >> 2, qq = sl & 3;              // edge slot / 16-B chunk
    int n = blockIdx.x * 16 + w * 4 + nl;        // one node per group, no stride loop
    float4 b2a = ((const float4*)b2)[qq * 2];    // channels qq*8 .. qq*8+3
    float4 b2b = ((const float4*)b2)[qq * 2 + 1];// channels qq*8+4 .. qq*8+7

    int beg = 0, cnt = 0;
    float ad = 0.f;
    if (n < N_NODES) { beg = rowptr[n]; cnt = deg[n]; ad = a2d[n]; }

    float acc[8] = {0.f, 0.f, 0.f, 0.f, 0.f, 0.f, 0.f, 0.f};
    float den = 0.f;
    int pkbase = nl * 17;
    for (int b16 = 0; b16 < cnt; b16 += 16) {    // group-divergent, exec-masked
        int li = b16 + sl;
        int idx = (li < cnt) ? csr_src[beg + li] : 0;
        float e = 0.f;
        if (li < cnt) e = __expf(lrelu(a2s[idx] + ad));
        den += e;
        pidx[w][pkbase + sl] = idx;              // same-wave stage (<=2-way banks)
        pe[w][pkbase + sl]   = e;
        #pragma unroll
        for (int p = 0; p < 4; p++) {            // fixed 4 steps: 4 rows in flight/group
            int id = pidx[w][pkbase + p * 4 + eg2];
            float ee = pe[w][pkbase + p * 4 + eg2];  // 0 for pads
            float g[8];
            ld8h(h2 + id * 32 + qq * 8, g);      // 16-B gather (8 halfs)
            acc[0] += ee * g[0]; acc[1] += ee * g[1];
            acc[2] += ee * g[2]; acc[3] += ee * g[3];
            acc[4] += ee * g[4]; acc[5] += ee * g[5];
            acc[6] += ee * g[6]; acc[7] += ee * g[7];
        }
    }
    // reduce across the 4 edge slots (within 16-lane group)
    #pragma unroll
    for (int j = 0; j < 8; j++) {
        float vv = acc[j];
        vv += __shfl_xor(vv, 4);
        vv += __shfl_xor(vv, 8);
        acc[j] = vv;
    }
    den += __shfl_xor(den, 1); den += __shfl_xor(den, 2);
    den += __shfl_xor(den, 4); den += __shfl_xor(den, 8);
    float inv = 1.f / (den + EPS);
    if (sl < 4) {                                // sl<4 => eg2=0, qq=sl: owns hf[qq*8..+7]
        float4 ha, hb;
        ha.x = acc[0] * inv + b2a.x; ha.y = acc[1] * inv + b2a.y;
        ha.z = acc[2] * inv + b2a.z; ha.w = acc[3] * inv + b2a.w;
        hb.x = acc[4] * inv + b2b.x; hb.y = acc[5] * inv + b2b.y;
        hb.z = acc[6] * inv + b2b.z; hb.w = acc[7] * inv + b2b.w;
        *(float4*)&hfv[w][nl * 36 + sl * 8]     = ha;   // same-wave stage
        *(float4*)&hfv[w][nl * 36 + sl * 8 + 4] = hb;
    }
    // epilogue: lane sl owns output slots 4sl..4sl+3 (slot = half*32 + c)
    if (n < N_NODES) {
        int half_o = sl >> 3, c4 = (sl & 7) * 4;
        __half* outp = half_o ? v : u;
        float r0 = half_o ? 0.f : mb1[c4 + 0];
        float r1 = half_o ? 0.f : mb1[c4 + 1];
        float r2 = half_o ? 0.f : mb1[c4 + 2];
        float r3 = half_o ? 0.f : mb1[c4 + 3];
        const float* hfp = &hfv[w][nl * 36];
        int s4 = sl * 4;                         // slot base
        #pragma unroll
        for (int k = 0; k < 32; k++) {
            float hk = hfp[k];                   // group broadcast (4nl bank offset)
            float4 wv = *(const float4*)&WT[k][s4];  // consecutive slots: 2-way max
            r0 += wv.x * hk; r1 += wv.y * hk;
            r2 += wv.z * hk; r3 += wv.w * hk;
        }
        __half2 p0, p1;
        p0.x = __float2half(r0); p0.y = __float2half(r1);
        p1.x = __float2half(r2); p1.y = __float2half(r3);
        uint2 st;
        st.x = *reinterpret_cast<unsigned int*>(&p0);
        st.y = *reinterpret_cast<unsigned int*>(&p1);
        *reinterpret_cast<uint2*>(outp + n * 32 + c4) = st;  // 8-B aligned store
    }
}

// ---------------------------------------------------------------- K-MLP: 8 lanes/edge, 4 edges/iter, fp16 u/v rows (1 line each)
#define MLP_BLOCKS 4096
__global__ void k_mlp(const int* __restrict__ ei, const __half* __restrict__ u,
                      const __half* __restrict__ v, const float* __restrict__ mw2,
                      const float* __restrict__ mb2, float* __restrict__ out) {
    int tid = threadIdx.x;
    int q = tid & 7;
    float4 w2q = ((const float4*)mw2)[q];
    float mb20 = mb2[0];
    int g = blockIdx.x * 32 + (tid >> 3);
    const int stride = MLP_BLOCKS * 32 * 4;
    for (int e = g * 4; e < N_EDGES; e += stride) {
        int eb = e;
        int e1 = (eb + 1 < N_EDGES) ? eb + 1 : eb;
        int e2 = (eb + 2 < N_EDGES) ? eb + 2 : eb;
        int e3 = (eb + 3 < N_EDGES) ? eb + 3 : eb;
        int sa = ei[eb], da = ei[N_EDGES + eb];
        int sb = ei[e1], db = ei[N_EDGES + e1];
        int sc = ei[e2], dc = ei[N_EDGES + e2];
        int sd = ei[e3], dd = ei[N_EDGES + e3];
        float4 ua = ld4h(u + sa * 32 + q * 4);
        float4 va = ld4h(v + da * 32 + q * 4);
        float4 ub = ld4h(u + sb * 32 + q * 4);
        float4 vb = ld4h(v + db * 32 + q * 4);
        float4 uc = ld4h(u + sc * 32 + q * 4);
        float4 vc = ld4h(v + dc * 32 + q * 4);
        float4 ud = ld4h(u + sd * 32 + q * 4);
        float4 vd = ld4h(v + dd * 32 + q * 4);
        float s0 = fmaxf(ua.x + va.x, 0.f) * w2q.x + fmaxf(ua.y + va.y, 0.f) * w2q.y
                 + fmaxf(ua.z + va.z, 0.f) * w2q.z + fmaxf(ua.w + va.w, 0.f) * w2q.w;
        float s1 = fmaxf(ub.x + vb.x, 0.f) * w2q.x + fmaxf(ub.y + vb.y, 0.f) * w2q.y
                 + fmaxf(ub.z + vb.z, 0.f) * w2q.z + fmaxf(ub.w + vb.w, 0.f) * w2q.w;
        float s2 = fmaxf(uc.x + vc.x, 0.f) * w2q.x + fmaxf(uc.y + vc.y, 0.f) * w2q.y
                 + fmaxf(uc.z + vc.z, 0.f) * w2q.z + fmaxf(uc.w + vc.w, 0.f) * w2q.w;
        float s3 = fmaxf(ud.x + vd.x, 0.f) * w2q.x + fmaxf(ud.y + vd.y, 0.f) * w2q.y
                 + fmaxf(ud.z + vd.z, 0.f) * w2q.z + fmaxf(ud.w + vd.w, 0.f) * w2q.w;
        s0 += __shfl_xor(s0, 1, 8); s0 += __shfl_xor(s0, 2, 8); s0 += __shfl_xor(s0, 4, 8);
        s1 += __shfl_xor(s1, 1, 8); s1 += __shfl_xor(s1, 2, 8); s1 += __shfl_xor(s1, 4, 8);
        s2 += __shfl_xor(s2, 1, 8); s2 += __shfl_xor(s2, 2, 8); s2 += __shfl_xor(s2, 4, 8);
        s3 += __shfl_xor(s3, 1, 8); s3 += __shfl_xor(s3, 2, 8); s3 += __shfl_xor(s3, 4, 8);
        if (q == 0) {
            out[eb] = fmaxf(s0 + mb20, 0.f);
            if (eb + 1 < N_EDGES) out[eb + 1] = fmaxf(s1 + mb20, 0.f);
            if (eb + 2 < N_EDGES) out[eb + 2] = fmaxf(s2 + mb20, 0.f);
            if (eb + 3 < N_EDGES) out[eb + 3] = fmaxf(s3 + mb20, 0.f);
        }
    }
}

// ---------------------------------------------------------------- launch
extern "C" void kernel_launch(void* const* d_in, const int* in_sizes, int n_in,
                              void* d_out, int out_size, void* d_ws, size_t ws_size,
                              hipStream_t stream) {
    const float* x    = (const float*)d_in[0];
    const int*   ei   = (const int*)d_in[1];
    const float* w1   = (const float*)d_in[2];
    const float* as1  = (const float*)d_in[3];
    const float* ad1  = (const float*)d_in[4];
    const float* b1   = (const float*)d_in[5];
    const float* w2   = (const float*)d_in[6];
    const float* as2  = (const float*)d_in[7];
    const float* ad2  = (const float*)d_in[8];
    const float* b2   = (const float*)d_in[9];
    const float* mw1  = (const float*)d_in[10];
    const float* mb1  = (const float*)d_in[11];
    const float* mw2  = (const float*)d_in[12];
    const float* mb2  = (const float*)d_in[13];
    float* out = (float*)d_out;

    const int N = N_NODES;
    // byte-offset workspace layout; p1/h2/u/v 64B-aligned (offsets verified)
    char* base   = (char*)d_ws;
    int* deg     = (int*)(base);                      // N*4
    int* rowptr  = (int*)(base + 400000);             // N*4
    int* bstart  = (int*)(base + 800000);             // (NBUCK+1)*4 = 788 B
    int* bh      = (int*)(base + 1200000);            // BLKB*NBUCK*4 = 306,544 B
    int* csr_src = (int*)(base + 1602048);            // E*4
    float* p1    = (float*)(base + 8002048);          // 8N*4   (%64==0)
    float* a1d   = (float*)(base + 11202048);         // 4N*4
    __half* h2   = (__half*)(base + 12802048);        // 32N*2  (%64==0)
    int* binned  = (int*)(base + 19202048);           // E*4 (disjoint lifetime vs h2 region tail)
    float* a2s   = (float*)(base + 25602048);         // N*4
    float* a2d   = (float*)(base + 26002048);         // N*4
    __half* u    = (__half*)(base + 26402048);        // 32N*2  (%64==0)
    __half* v    = (__half*)(base + 32802048);        // 32N*2  (%64==0)
    float* qv    = (float*)(base + 39202048);         // 24

    const int nb = (N + 255) / 256;

    kA_hist<<<BLKB, 256, 0, stream>>>(ei, bh);
    kS1<<<NBUCK, 256, 0, stream>>>(bh, bstart);
    kS2<<<1, 256, 0, stream>>>(bstart);
    kB_bin<<<BLKB, 256, 0, stream>>>(ei, bh, bstart, binned);
    kC_sort<<<NBUCK, 256, 0, stream>>>(bstart, binned, deg, rowptr, csr_src);

    k_q<<<1, 32, 0, stream>>>(w1, as1, ad1, qv);
    k_node1<<<nb, 256, 0, stream>>>(x, qv, a1d, p1);

    k_gat1<<<G1_BLOCKS, 256, 0, stream>>>(rowptr, deg, csr_src, p1, w1, a1d,
                                          b1, w2, as2, ad2, h2, a2s, a2d);

    k_gat2<<<G2_BLOCKS, 256, 0, stream>>>(rowptr, deg, csr_src, h2, a2s, a2d, b2,
                                          mw1, mb1, u, v);

    k_mlp<<<MLP_BLOCKS, 256, 0, stream>>>(ei, u, v, mw2, mb2, out);
}

// Round 15
// 245.175 us; speedup vs baseline: 1.1711x; 1.0224x over previous
//
#include <hip/hip_runtime.h>
#include <hip/hip_fp16.h>
#include <math.h>

#define N_NODES 100000
#define N_EDGES 1600000
#define NEG_SLOPE 0.2f
#define EPS 1e-16f

// bucket sort geometry: 196 buckets of 512 nodes; 391 blocks x 4096 edges
#define NBUCK 196
#define CHUNK 4096
#define BLKB 391

typedef _Float16 f16x8 __attribute__((ext_vector_type(8)));
typedef float f32x4 __attribute__((ext_vector_type(4)));

__device__ __forceinline__ float lrelu(float v) { return v > 0.f ? v : NEG_SLOPE * v; }

// load 4 halfs -> float4 (single 8B load)
__device__ __forceinline__ float4 ld4h(const __half* p) {
    uint2 r = *(const uint2*)p;
    __half2 h0 = *reinterpret_cast<const __half2*>(&r.x);
    __half2 h1 = *reinterpret_cast<const __half2*>(&r.y);
    float2 f0 = __half22float2(h0), f1 = __half22float2(h1);
    return make_float4(f0.x, f0.y, f1.x, f1.y);
}

// load 8 halfs -> 8 floats (single 16B load)
__device__ __forceinline__ void ld8h(const __half* p, float* f) {
    uint4 r = *(const uint4*)p;
    __half2 h0 = *reinterpret_cast<const __half2*>(&r.x);
    __half2 h1 = *reinterpret_cast<const __half2*>(&r.y);
    __half2 h2 = *reinterpret_cast<const __half2*>(&r.z);
    __half2 h3 = *reinterpret_cast<const __half2*>(&r.w);
    float2 f0 = __half22float2(h0), f1 = __half22float2(h1);
    float2 f2 = __half22float2(h2), f3 = __half22float2(h3);
    f[0] = f0.x; f[1] = f0.y; f[2] = f1.x; f[3] = f1.y;
    f[4] = f2.x; f[5] = f2.y; f[6] = f3.x; f[7] = f3.y;
}

// ---------------------------------------------------------------- Pass A: per-block coarse histogram (LDS only)
__global__ void kA_hist(const int* __restrict__ ei, int* __restrict__ bh) {
    __shared__ int hist[NBUCK];
    int tid = threadIdx.x, b = blockIdx.x;
    if (tid < NBUCK) hist[tid] = 0;
    __syncthreads();
    int base = b * CHUNK;
    #pragma unroll
    for (int i = 0; i < CHUNK / 256; i++) {
        int e = base + i * 256 + tid;
        if (e < N_EDGES) {
            int dst = ei[N_EDGES + e];
            atomicAdd(&hist[dst >> 9], 1);
        }
    }
    __syncthreads();
    if (tid < NBUCK) bh[b * NBUCK + tid] = hist[tid];
}

// ---------------------------------------------------------------- S1: column scan of bh (one block per bucket)
__global__ void kS1(int* __restrict__ bh, int* __restrict__ bucketStart) {
    __shared__ int tsum[256];
    int k = blockIdx.x, t = threadIdx.x;
    int j0 = 2 * t, j1 = 2 * t + 1;
    int v0 = (j0 < BLKB) ? bh[j0 * NBUCK + k] : 0;
    int v1 = (j1 < BLKB) ? bh[j1 * NBUCK + k] : 0;
    int s = v0 + v1;
    tsum[t] = s;
    __syncthreads();
    for (int off = 1; off < 256; off <<= 1) {
        int tv = (t >= off) ? tsum[t - off] : 0;
        __syncthreads();
        tsum[t] += tv;
        __syncthreads();
    }
    int excl = tsum[t] - s;
    if (j0 < BLKB) bh[j0 * NBUCK + k] = excl;
    if (j1 < BLKB) bh[j1 * NBUCK + k] = excl + v0;
    if (t == 255) bucketStart[k] = tsum[255];   // column total (scanned by S2)
}

// ---------------------------------------------------------------- S2: scan bucket totals -> bucket starts (+ total at [NBUCK])
__global__ void kS2(int* __restrict__ bucketStart) {
    __shared__ int tmp[256];
    int t = threadIdx.x;
    int v = (t < NBUCK) ? bucketStart[t] : 0;
    tmp[t] = v;
    __syncthreads();
    for (int off = 1; off < 256; off <<= 1) {
        int tv = (t >= off) ? tmp[t - off] : 0;
        __syncthreads();
        tmp[t] += tv;
        __syncthreads();
    }
    if (t < NBUCK) bucketStart[t] = tmp[t] - v;
    if (t == NBUCK - 1) bucketStart[NBUCK] = tmp[t];
}

// ---------------------------------------------------------------- Pass B: bin edges by coarse bucket (LDS cursors, coalesced-run writes)
__global__ void kB_bin(const int* __restrict__ ei, const int* __restrict__ bh,
                       const int* __restrict__ bucketStart, int* __restrict__ binned) {
    __shared__ int cur[NBUCK];
    int tid = threadIdx.x, b = blockIdx.x;
    if (tid < NBUCK) cur[tid] = bucketStart[tid] + bh[b * NBUCK + tid];
    __syncthreads();
    int base = b * CHUNK;
    #pragma unroll
    for (int i = 0; i < CHUNK / 256; i++) {
        int e = base + i * 256 + tid;
        if (e < N_EDGES) {
            int src = ei[e], dst = ei[N_EDGES + e];
            int pos = atomicAdd(&cur[dst >> 9], 1);
            binned[pos] = src | ((dst & 511) << 17);
        }
    }
}

// ---------------------------------------------------------------- Pass C: per-bucket counting sort -> deg, rowptr, csr_src
__global__ void kC_sort(const int* __restrict__ bucketStart, const int* __restrict__ binned,
                        int* __restrict__ deg, int* __restrict__ rowptr,
                        int* __restrict__ csr_src) {
    __shared__ int cnt[512];
    __shared__ int pfx[512];
    __shared__ int bsum[256];
    int t = threadIdx.x, k = blockIdx.x;
    int s0 = bucketStart[k], s1 = bucketStart[k + 1];
    cnt[t] = 0; cnt[t + 256] = 0;
    __syncthreads();
    for (int i = s0 + t; i < s1; i += 256)
        atomicAdd(&cnt[binned[i] >> 17], 1);
    __syncthreads();
    int a0 = cnt[2 * t], a1 = cnt[2 * t + 1];
    int s = a0 + a1;
    bsum[t] = s;
    __syncthreads();
    for (int off = 1; off < 256; off <<= 1) {
        int tv = (t >= off) ? bsum[t - off] : 0;
        __syncthreads();
        bsum[t] += tv;
        __syncthreads();
    }
    int excl = bsum[t] - s;
    pfx[2 * t] = excl;
    pfx[2 * t + 1] = excl + a0;
    int nb0 = k << 9;
    int n0 = nb0 + 2 * t, n1 = nb0 + 2 * t + 1;
    if (n0 < N_NODES) { deg[n0] = a0; rowptr[n0] = s0 + excl; }
    if (n1 < N_NODES) { deg[n1] = a1; rowptr[n1] = s0 + excl + a0; }
    __syncthreads();
    for (int i = s0 + t; i < s1; i += 256) {
        int pkd = binned[i];
        int pos = s0 + atomicAdd(&pfx[pkd >> 17], 1);
        csr_src[pos] = pkd & 0x1FFFF;
    }
}

// ---------------------------------------------------------------- K-Q: qs[h] = W1_h^T a_src_h, qd[h] = W1_h^T a_dst_h  (24 floats)
__global__ void k_q(const float* __restrict__ w1, const float* __restrict__ as1,
                    const float* __restrict__ ad1, float* __restrict__ qv) {
    int t = threadIdx.x;
    if (t >= 24) return;
    int c = t % 3, h = (t / 3) % 4, side = t / 12;
    const float* att = side ? ad1 : as1;
    float acc = 0.f;
    for (int cc = 0; cc < 32; cc++)
        acc += att[h * 32 + cc] * w1[(h * 32 + cc) * 3 + c];
    qv[t] = acc;
}

// ---------------------------------------------------------------- K-NODE1: a1d = x.qd ; p1h[n] = fp16 {a1s[4], x0,x1,x2,1} (16B row)
__global__ void k_node1(const float* __restrict__ x, const float* __restrict__ qv,
                        float* __restrict__ a1d, __half* __restrict__ p1h) {
    int n = blockIdx.x * blockDim.x + threadIdx.x;
    if (n >= N_NODES) return;
    float x0 = x[n * 3], x1 = x[n * 3 + 1], x2 = x[n * 3 + 2];
    float s0 = x0 * qv[0]  + x1 * qv[1]  + x2 * qv[2];
    float s1 = x0 * qv[3]  + x1 * qv[4]  + x2 * qv[5];
    float s2 = x0 * qv[6]  + x1 * qv[7]  + x2 * qv[8];
    float s3 = x0 * qv[9]  + x1 * qv[10] + x2 * qv[11];
    float4 d;
    d.x = x0 * qv[12] + x1 * qv[13] + x2 * qv[14];
    d.y = x0 * qv[15] + x1 * qv[16] + x2 * qv[17];
    d.z = x0 * qv[18] + x1 * qv[19] + x2 * qv[20];
    d.w = x0 * qv[21] + x1 * qv[22] + x2 * qv[23];
    ((float4*)a1d)[n] = d;
    __half2 h0 = __floats2half2_rn(s0, s1);
    __half2 h1 = __floats2half2_rn(s2, s3);
    __half2 h2v = __floats2half2_rn(x0, x1);
    __half2 h3 = __floats2half2_rn(x2, 1.f);
    uint4 st;
    st.x = *reinterpret_cast<unsigned int*>(&h0);
    st.y = *reinterpret_cast<unsigned int*>(&h1);
    st.z = *reinterpret_cast<unsigned int*>(&h2v);
    st.w = *reinterpret_cast<unsigned int*>(&h3);
    *reinterpret_cast<uint4*>(p1h + n * 8) = st;
}

// ---------------------------------------------------------------- K-GAT1 v7: fp16 p1 rows (1 gather/edge) + MFMA phase B
// Phase A: 4 lanes/node partition edges stride-4; each edge = ONE 16-B gather
// of p1h {a1s[4],x0,x1,x2,1} (was two 16-B loads of fp32 p1). Table 3.2->1.6MB
// (per-XCD L2 resident). 4 edges/iter unroll keeps 4 gathers in flight.
#define G1_BLOCKS ((N_NODES + 63) / 64)
__global__ void k_gat1(const int* __restrict__ rowptr, const int* __restrict__ deg,
                       const int* __restrict__ csr_src,
                       const __half* __restrict__ p1h, const float* __restrict__ w1,
                       const float* __restrict__ a1d,
                       const float* __restrict__ b1, const float* __restrict__ w2,
                       const float* __restrict__ as2, const float* __restrict__ ad2,
                       __half* __restrict__ h2, float* __restrict__ a2s, float* __restrict__ a2d) {
    __shared__ float sm[64][16];                        // per-node: 4 heads x {s0,s1,s2,den}
    __shared__ __align__(16) __half F1h[4][16][136];    // per-wave f1, fp16, padded rows
    int tid = threadIdx.x;
    int wave = tid >> 6, lane = tid & 63;

    // ---- phase A: node = block*64 + wave*16 + (lane>>2); lane&3 = edge phase = head slot
    int nl = wave * 16 + (lane >> 2);
    int h  = lane & 3;
    int n  = blockIdx.x * 64 + nl;
    if (n < N_NODES) {
        float4 ad4 = ((const float4*)a1d)[n];          // broadcast across the quad
        float adv[4] = {ad4.x, ad4.y, ad4.z, ad4.w};
        int beg = rowptr[n], cnt = deg[n];
        float acc[4][4];                                // [head][{s0,s1,s2,den}]
        #pragma unroll
        for (int hh = 0; hh < 4; hh++)
            acc[hh][0] = acc[hh][1] = acc[hh][2] = acc[hh][3] = 0.f;
        int t = h;
        for (; t + 12 < cnt; t += 16) {                 // 4 edges/iter, 4 gathers in flight
            int i0 = csr_src[beg + t],     i1 = csr_src[beg + t + 4];
            int i2 = csr_src[beg + t + 8], i3 = csr_src[beg + t + 12];
            float g0[8], g1[8], g2[8], g3[8];
            ld8h(p1h + i0 * 8, g0);
            ld8h(p1h + i1 * 8, g1);
            ld8h(p1h + i2 * 8, g2);
            ld8h(p1h + i3 * 8, g3);
            #pragma unroll
            for (int hh = 0; hh < 4; hh++) {
                float e0 = __expf(lrelu(g0[hh] + adv[hh]));
                float e1 = __expf(lrelu(g1[hh] + adv[hh]));
                float e2 = __expf(lrelu(g2[hh] + adv[hh]));
                float e3 = __expf(lrelu(g3[hh] + adv[hh]));
                acc[hh][0] += e0 * g0[4] + e1 * g1[4] + e2 * g2[4] + e3 * g3[4];
                acc[hh][1] += e0 * g0[5] + e1 * g1[5] + e2 * g2[5] + e3 * g3[5];
                acc[hh][2] += e0 * g0[6] + e1 * g1[6] + e2 * g2[6] + e3 * g3[6];
                acc[hh][3] += e0 + e1 + e2 + e3;
            }
        }
        for (; t < cnt; t += 4) {                       // tail: up to 3 edges per lane
            int i0 = csr_src[beg + t];
            float g0[8];
            ld8h(p1h + i0 * 8, g0);
            #pragma unroll
            for (int hh = 0; hh < 4; hh++) {
                float e0 = __expf(lrelu(g0[hh] + adv[hh]));
                acc[hh][0] += e0 * g0[4];
                acc[hh][1] += e0 * g0[5];
                acc[hh][2] += e0 * g0[6];
                acc[hh][3] += e0;
            }
        }
        // 4-lane butterfly (quad is exec-uniform: same n) — every lane gets full sums
        #pragma unroll
        for (int hh = 0; hh < 4; hh++) {
            #pragma unroll
            for (int cc = 0; cc < 4; cc++) {
                float vv = acc[hh][cc];
                vv += __shfl_xor(vv, 1);
                vv += __shfl_xor(vv, 2);
                acc[hh][cc] = vv;
            }
        }
        float4 r;   // lane writes its own head's slice (static-index select, once per node)
        r.x = h == 0 ? acc[0][0] : h == 1 ? acc[1][0] : h == 2 ? acc[2][0] : acc[3][0];
        r.y = h == 0 ? acc[0][1] : h == 1 ? acc[1][1] : h == 2 ? acc[2][1] : acc[3][1];
        r.z = h == 0 ? acc[0][2] : h == 1 ? acc[1][2] : h == 2 ? acc[2][2] : acc[3][2];
        r.w = h == 0 ? acc[0][3] : h == 1 ? acc[1][3] : h == 2 ? acc[2][3] : acc[3][3];
        *(float4*)&sm[nl][h * 4] = r;
    }
    // same-wave LDS write->read below: no barrier needed

    // ---- B-fragments: Bf[tile][ks], lane elem e = w2[tile*16+(lane&15)][ks*32+(lane>>4)*8+e]
    f16x8 Bf[2][4];
    {
        int bn = lane & 15, bg = lane >> 4;
        #pragma unroll
        for (int tile = 0; tile < 2; tile++) {
            const float* wrow = w2 + (tile * 16 + bn) * 128 + bg * 8;
            #pragma unroll
            for (int ks = 0; ks < 4; ks++) {
                const float4* wp = (const float4*)(wrow + ks * 32);
                float4 u0 = wp[0], u1 = wp[1];
                f16x8 bf;
                bf[0] = (_Float16)u0.x; bf[1] = (_Float16)u0.y;
                bf[2] = (_Float16)u0.z; bf[3] = (_Float16)u0.w;
                bf[4] = (_Float16)u1.x; bf[5] = (_Float16)u1.y;
                bf[6] = (_Float16)u1.z; bf[7] = (_Float16)u1.w;
                Bf[tile][ks] = bf;
            }
        }
    }

    // ---- phase B step 1: f1 (fp16) for the wave's 16 nodes -> F1h
    int j = lane, j2 = lane + 64;
    int h0 = j >> 5;
    float wa0 = w1[j * 3], wa1 = w1[j * 3 + 1], wa2 = w1[j * 3 + 2];
    float wb0 = w1[j2 * 3], wb1 = w1[j2 * 3 + 1], wb2 = w1[j2 * 3 + 2];
    float b1j = b1[j], b1j2 = b1[j2];

    #pragma unroll 1
    for (int i = 0; i < 16; i++) {
        int n2 = blockIdx.x * 64 + wave * 16 + i;
        if (n2 >= N_NODES) break;
        const float* S = sm[wave * 16 + i];
        float v0 = (wa0 * S[h0 * 4] + wa1 * S[h0 * 4 + 1] + wa2 * S[h0 * 4 + 2])
                   / (S[h0 * 4 + 3] + EPS) + b1j;
        float v1 = (wb0 * S[(2 + h0) * 4] + wb1 * S[(2 + h0) * 4 + 1] + wb2 * S[(2 + h0) * 4 + 2])
                   / (S[(2 + h0) * 4 + 3] + EPS) + b1j2;
        float e0 = v0 > 0.f ? v0 : __expf(v0) - 1.f;   // ELU via fast exp
        float e1 = v1 > 0.f ? v1 : __expf(v1) - 1.f;
        F1h[wave][i][j]  = __float2half(e0);
        F1h[wave][i][j2] = __float2half(e1);
    }

    // ---- phase B step 2: 8 MFMA (2 col-tiles x 4 K-steps); A-frag via ds_read_b128
    f32x4 d0 = {0.f, 0.f, 0.f, 0.f}, d1 = {0.f, 0.f, 0.f, 0.f};
    {
        int am = lane & 15, ag = lane >> 4;
        const __half* Arow = &F1h[wave][am][0];
        #pragma unroll
        for (int ks = 0; ks < 4; ks++) {
            f16x8 af = *(const f16x8*)&Arow[ks * 32 + ag * 8];   // 16B-aligned
            d0 = __builtin_amdgcn_mfma_f32_16x16x32_f16(af, Bf[0][ks], d0, 0, 0, 0);
            d1 = __builtin_amdgcn_mfma_f32_16x16x32_f16(af, Bf[1][ks], d1, 0, 0, 0);
        }
    }

    // ---- epilogue: D col = lane&15 (channel), row = (lane>>4)*4+r (node)
    {
        int ch = lane & 15, rg = lane >> 4;
        float as2a = as2[ch], as2b = as2[ch + 16];
        float ad2a = ad2[ch], ad2b = ad2[ch + 16];
        #pragma unroll
        for (int r = 0; r < 4; r++) {
            int n2 = blockIdx.x * 64 + wave * 16 + rg * 4 + r;
            float va = d0[r], vb = d1[r];
            if (n2 < N_NODES) {
                h2[n2 * 32 + ch]      = __float2half(va);
                h2[n2 * 32 + ch + 16] = __float2half(vb);
            }
            float ps = va * as2a + vb * as2b;
            float pd = va * ad2a + vb * ad2b;
            ps += __shfl_xor(ps, 1); ps += __shfl_xor(ps, 2);
            ps += __shfl_xor(ps, 4); ps += __shfl_xor(ps, 8);
            pd += __shfl_xor(pd, 1); pd += __shfl_xor(pd, 2);
            pd += __shfl_xor(pd, 4); pd += __shfl_xor(pd, 8);
            if (ch == 0 && n2 < N_NODES) { a2s[n2] = ps; a2d[n2] = pd; }
        }
    }
}

// ---------------------------------------------------------------- K-GAT2 v6: bank-conflict-free LDS layouts
#define G2_BLOCKS ((N_NODES + 15) / 16)
__global__ void k_gat2(const int* __restrict__ rowptr, const int* __restrict__ deg,
                       const int* __restrict__ csr_src,
                       const __half* __restrict__ h2, const float* __restrict__ a2s,
                       const float* __restrict__ a2d, const float* __restrict__ b2,
                       const float* __restrict__ mw1, const float* __restrict__ mb1,
                       __half* __restrict__ u, __half* __restrict__ v) {
    __shared__ __align__(16) float WT[32][68];  // WT[k][slot]: slot s = half*32+c -> mw1[c][half*32+k]
    __shared__ int   pidx[4][68];               // per-wave staged idx, group stride 17
    __shared__ float pe[4][68];                 // per-wave staged e,   group stride 17
    __shared__ float hfv[4][144];               // per-wave hf, group row stride 36
    int tid = threadIdx.x;
    for (int i = tid; i < 2048; i += 256) {
        int s = i >> 5, k = i & 31;
        WT[k][s] = mw1[(s & 31) * 64 + (s >> 5) * 32 + k];
    }
    __syncthreads();
    int lane = tid & 63, w = tid >> 6;
    int nl = lane >> 4, sl = lane & 15;          // group (node) / sub-lane
    int eg2 = sl >> 2, qq = sl & 3;              // edge slot / 16-B chunk
    int n = blockIdx.x * 16 + w * 4 + nl;        // one node per group, no stride loop
    float4 b2a = ((const float4*)b2)[qq * 2];    // channels qq*8 .. qq*8+3
    float4 b2b = ((const float4*)b2)[qq * 2 + 1];// channels qq*8+4 .. qq*8+7

    int beg = 0, cnt = 0;
    float ad = 0.f;
    if (n < N_NODES) { beg = rowptr[n]; cnt = deg[n]; ad = a2d[n]; }

    float acc[8] = {0.f, 0.f, 0.f, 0.f, 0.f, 0.f, 0.f, 0.f};
    float den = 0.f;
    int pkbase = nl * 17;
    for (int b16 = 0; b16 < cnt; b16 += 16) {    // group-divergent, exec-masked
        int li = b16 + sl;
        int idx = (li < cnt) ? csr_src[beg + li] : 0;
        float e = 0.f;
        if (li < cnt) e = __expf(lrelu(a2s[idx] + ad));
        den += e;
        pidx[w][pkbase + sl] = idx;              // same-wave stage (<=2-way banks)
        pe[w][pkbase + sl]   = e;
        #pragma unroll
        for (int p = 0; p < 4; p++) {            // fixed 4 steps: 4 rows in flight/group
            int id = pidx[w][pkbase + p * 4 + eg2];
            float ee = pe[w][pkbase + p * 4 + eg2];  // 0 for pads
            float g[8];
            ld8h(h2 + id * 32 + qq * 8, g);      // 16-B gather (8 halfs)
            acc[0] += ee * g[0]; acc[1] += ee * g[1];
            acc[2] += ee * g[2]; acc[3] += ee * g[3];
            acc[4] += ee * g[4]; acc[5] += ee * g[5];
            acc[6] += ee * g[6]; acc[7] += ee * g[7];
        }
    }
    // reduce across the 4 edge slots (within 16-lane group)
    #pragma unroll
    for (int j = 0; j < 8; j++) {
        float vv = acc[j];
        vv += __shfl_xor(vv, 4);
        vv += __shfl_xor(vv, 8);
        acc[j] = vv;
    }
    den += __shfl_xor(den, 1); den += __shfl_xor(den, 2);
    den += __shfl_xor(den, 4); den += __shfl_xor(den, 8);
    float inv = 1.f / (den + EPS);
    if (sl < 4) {                                // sl<4 => eg2=0, qq=sl: owns hf[qq*8..+7]
        float4 ha, hb;
        ha.x = acc[0] * inv + b2a.x; ha.y = acc[1] * inv + b2a.y;
        ha.z = acc[2] * inv + b2a.z; ha.w = acc[3] * inv + b2a.w;
        hb.x = acc[4] * inv + b2b.x; hb.y = acc[5] * inv + b2b.y;
        hb.z = acc[6] * inv + b2b.z; hb.w = acc[7] * inv + b2b.w;
        *(float4*)&hfv[w][nl * 36 + sl * 8]     = ha;   // same-wave stage
        *(float4*)&hfv[w][nl * 36 + sl * 8 + 4] = hb;
    }
    // epilogue: lane sl owns output slots 4sl..4sl+3 (slot = half*32 + c)
    if (n < N_NODES) {
        int half_o = sl >> 3, c4 = (sl & 7) * 4;
        __half* outp = half_o ? v : u;
        float r0 = half_o ? 0.f : mb1[c4 + 0];
        float r1 = half_o ? 0.f : mb1[c4 + 1];
        float r2 = half_o ? 0.f : mb1[c4 + 2];
        float r3 = half_o ? 0.f : mb1[c4 + 3];
        const float* hfp = &hfv[w][nl * 36];
        int s4 = sl * 4;                         // slot base
        #pragma unroll
        for (int k = 0; k < 32; k++) {
            float hk = hfp[k];                   // group broadcast (4nl bank offset)
            float4 wv = *(const float4*)&WT[k][s4];  // consecutive slots: 2-way max
            r0 += wv.x * hk; r1 += wv.y * hk;
            r2 += wv.z * hk; r3 += wv.w * hk;
        }
        __half2 p0, p1;
        p0.x = __float2half(r0); p0.y = __float2half(r1);
        p1.x = __float2half(r2); p1.y = __float2half(r3);
        uint2 st;
        st.x = *reinterpret_cast<unsigned int*>(&p0);
        st.y = *reinterpret_cast<unsigned int*>(&p1);
        *reinterpret_cast<uint2*>(outp + n * 32 + c4) = st;  // 8-B aligned store
    }
}

// ---------------------------------------------------------------- K-MLP: 8 lanes/edge, 4 edges/iter, fp16 u/v rows (1 line each)
#define MLP_BLOCKS 4096
__global__ void k_mlp(const int* __restrict__ ei, const __half* __restrict__ u,
                      const __half* __restrict__ v, const float* __restrict__ mw2,
                      const float* __restrict__ mb2, float* __restrict__ out) {
    int tid = threadIdx.x;
    int q = tid & 7;
    float4 w2q = ((const float4*)mw2)[q];
    float mb20 = mb2[0];
    int g = blockIdx.x * 32 + (tid >> 3);
    const int stride = MLP_BLOCKS * 32 * 4;
    for (int e = g * 4; e < N_EDGES; e += stride) {
        int eb = e;
        int e1 = (eb + 1 < N_EDGES) ? eb + 1 : eb;
        int e2 = (eb + 2 < N_EDGES) ? eb + 2 : eb;
        int e3 = (eb + 3 < N_EDGES) ? eb + 3 : eb;
        int sa = ei[eb], da = ei[N_EDGES + eb];
        int sb = ei[e1], db = ei[N_EDGES + e1];
        int sc = ei[e2], dc = ei[N_EDGES + e2];
        int sd = ei[e3], dd = ei[N_EDGES + e3];
        float4 ua = ld4h(u + sa * 32 + q * 4);
        float4 va = ld4h(v + da * 32 + q * 4);
        float4 ub = ld4h(u + sb * 32 + q * 4);
        float4 vb = ld4h(v + db * 32 + q * 4);
        float4 uc = ld4h(u + sc * 32 + q * 4);
        float4 vc = ld4h(v + dc * 32 + q * 4);
        float4 ud = ld4h(u + sd * 32 + q * 4);
        float4 vd = ld4h(v + dd * 32 + q * 4);
        float s0 = fmaxf(ua.x + va.x, 0.f) * w2q.x + fmaxf(ua.y + va.y, 0.f) * w2q.y
                 + fmaxf(ua.z + va.z, 0.f) * w2q.z + fmaxf(ua.w + va.w, 0.f) * w2q.w;
        float s1 = fmaxf(ub.x + vb.x, 0.f) * w2q.x + fmaxf(ub.y + vb.y, 0.f) * w2q.y
                 + fmaxf(ub.z + vb.z, 0.f) * w2q.z + fmaxf(ub.w + vb.w, 0.f) * w2q.w;
        float s2 = fmaxf(uc.x + vc.x, 0.f) * w2q.x + fmaxf(uc.y + vc.y, 0.f) * w2q.y
                 + fmaxf(uc.z + vc.z, 0.f) * w2q.z + fmaxf(uc.w + vc.w, 0.f) * w2q.w;
        float s3 = fmaxf(ud.x + vd.x, 0.f) * w2q.x + fmaxf(ud.y + vd.y, 0.f) * w2q.y
                 + fmaxf(ud.z + vd.z, 0.f) * w2q.z + fmaxf(ud.w + vd.w, 0.f) * w2q.w;
        s0 += __shfl_xor(s0, 1, 8); s0 += __shfl_xor(s0, 2, 8); s0 += __shfl_xor(s0, 4, 8);
        s1 += __shfl_xor(s1, 1, 8); s1 += __shfl_xor(s1, 2, 8); s1 += __shfl_xor(s1, 4, 8);
        s2 += __shfl_xor(s2, 1, 8); s2 += __shfl_xor(s2, 2, 8); s2 += __shfl_xor(s2, 4, 8);
        s3 += __shfl_xor(s3, 1, 8); s3 += __shfl_xor(s3, 2, 8); s3 += __shfl_xor(s3, 4, 8);
        if (q == 0) {
            out[eb] = fmaxf(s0 + mb20, 0.f);
            if (eb + 1 < N_EDGES) out[eb + 1] = fmaxf(s1 + mb20, 0.f);
            if (eb + 2 < N_EDGES) out[eb + 2] = fmaxf(s2 + mb20, 0.f);
            if (eb + 3 < N_EDGES) out[eb + 3] = fmaxf(s3 + mb20, 0.f);
        }
    }
}

// ---------------------------------------------------------------- launch
extern "C" void kernel_launch(void* const* d_in, const int* in_sizes, int n_in,
                              void* d_out, int out_size, void* d_ws, size_t ws_size,
                              hipStream_t stream) {
    const float* x    = (const float*)d_in[0];
    const int*   ei   = (const int*)d_in[1];
    const float* w1   = (const float*)d_in[2];
    const float* as1  = (const float*)d_in[3];
    const float* ad1  = (const float*)d_in[4];
    const float* b1   = (const float*)d_in[5];
    const float* w2   = (const float*)d_in[6];
    const float* as2  = (const float*)d_in[7];
    const float* ad2  = (const float*)d_in[8];
    const float* b2   = (const float*)d_in[9];
    const float* mw1  = (const float*)d_in[10];
    const float* mb1  = (const float*)d_in[11];
    const float* mw2  = (const float*)d_in[12];
    const float* mb2  = (const float*)d_in[13];
    float* out = (float*)d_out;

    const int N = N_NODES;
    // byte-offset workspace layout; p1h/h2/u/v 64B-aligned (offsets verified)
    char* base   = (char*)d_ws;
    int* deg     = (int*)(base);                      // N*4
    int* rowptr  = (int*)(base + 400000);             // N*4
    int* bstart  = (int*)(base + 800000);             // (NBUCK+1)*4 = 788 B
    int* bh      = (int*)(base + 1200000);            // BLKB*NBUCK*4 = 306,544 B
    int* csr_src = (int*)(base + 1602048);            // E*4
    __half* p1h  = (__half*)(base + 8002048);         // 8N*2   (%64==0)
    float* a1d   = (float*)(base + 11202048);         // 4N*4
    __half* h2   = (__half*)(base + 12802048);        // 32N*2  (%64==0)
    int* binned  = (int*)(base + 19202048);           // E*4 (disjoint lifetime vs h2 region tail)
    float* a2s   = (float*)(base + 25602048);         // N*4
    float* a2d   = (float*)(base + 26002048);         // N*4
    __half* u    = (__half*)(base + 26402048);        // 32N*2  (%64==0)
    __half* v    = (__half*)(base + 32802048);        // 32N*2  (%64==0)
    float* qv    = (float*)(base + 39202048);         // 24

    const int nb = (N + 255) / 256;

    kA_hist<<<BLKB, 256, 0, stream>>>(ei, bh);
    kS1<<<NBUCK, 256, 0, stream>>>(bh, bstart);
    kS2<<<1, 256, 0, stream>>>(bstart);
    kB_bin<<<BLKB, 256, 0, stream>>>(ei, bh, bstart, binned);
    kC_sort<<<NBUCK, 256, 0, stream>>>(bstart, binned, deg, rowptr, csr_src);

    k_q<<<1, 32, 0, stream>>>(w1, as1, ad1, qv);
    k_node1<<<nb, 256, 0, stream>>>(x, qv, a1d, p1h);

    k_gat1<<<G1_BLOCKS, 256, 0, stream>>>(rowptr, deg, csr_src, p1h, w1, a1d,
                                          b1, w2, as2, ad2, h2, a2s, a2d);

    k_gat2<<<G2_BLOCKS, 256, 0, stream>>>(rowptr, deg, csr_src, h2, a2s, a2d, b2,
                                          mw1, mb1, u, v);

    k_mlp<<<MLP_BLOCKS, 256, 0, stream>>>(ei, u, v, mw2, mb2, out);
}

// Round 16
// 238.292 us; speedup vs baseline: 1.2049x; 1.0289x over previous
//
#include <hip/hip_runtime.h>
#include <hip/hip_fp16.h>
#include <math.h>

#define N_NODES 100000
#define N_EDGES 1600000
#define NEG_SLOPE 0.2f
#define EPS 1e-16f

// bucket sort geometry: 196 buckets of 512 nodes; 391 blocks x 4096 edges
#define NBUCK 196
#define CHUNK 4096
#define BLKB 391
#define EBUF_CAP 9216   // bucket mean 8192, sigma ~90; cap = mean+11sigma, global fallback

typedef _Float16 f16x8 __attribute__((ext_vector_type(8)));
typedef float f32x4 __attribute__((ext_vector_type(4)));

__device__ __forceinline__ float lrelu(float v) { return v > 0.f ? v : NEG_SLOPE * v; }

// load 4 halfs -> float4 (single 8B load)
__device__ __forceinline__ float4 ld4h(const __half* p) {
    uint2 r = *(const uint2*)p;
    __half2 h0 = *reinterpret_cast<const __half2*>(&r.x);
    __half2 h1 = *reinterpret_cast<const __half2*>(&r.y);
    float2 f0 = __half22float2(h0), f1 = __half22float2(h1);
    return make_float4(f0.x, f0.y, f1.x, f1.y);
}

// load 8 halfs -> 8 floats (single 16B load)
__device__ __forceinline__ void ld8h(const __half* p, float* f) {
    uint4 r = *(const uint4*)p;
    __half2 h0 = *reinterpret_cast<const __half2*>(&r.x);
    __half2 h1 = *reinterpret_cast<const __half2*>(&r.y);
    __half2 h2 = *reinterpret_cast<const __half2*>(&r.z);
    __half2 h3 = *reinterpret_cast<const __half2*>(&r.w);
    float2 f0 = __half22float2(h0), f1 = __half22float2(h1);
    float2 f2 = __half22float2(h2), f3 = __half22float2(h3);
    f[0] = f0.x; f[1] = f0.y; f[2] = f1.x; f[3] = f1.y;
    f[4] = f2.x; f[5] = f2.y; f[6] = f3.x; f[7] = f3.y;
}

// ---------------------------------------------------------------- Pass A (fused): coarse histogram + k_q + k_node1
// 391 blocks x 256 = 100096 threads >= N_NODES: block b preps nodes b*256..+255
// alongside its edge-chunk histogram. qv computed per block in LDS (24x32 MACs).
__global__ void kA_hist_node(const int* __restrict__ ei, int* __restrict__ bh,
                             const float* __restrict__ x, const float* __restrict__ w1,
                             const float* __restrict__ as1, const float* __restrict__ ad1,
                             float* __restrict__ a1d, __half* __restrict__ p1h) {
    __shared__ int hist[NBUCK];
    __shared__ float qvs[24];
    int tid = threadIdx.x, b = blockIdx.x;
    if (tid < NBUCK) hist[tid] = 0;
    if (tid >= 224 && tid < 248) {          // threads 224..247 compute qv (disjoint from hist-zero range)
        int t = tid - 224;
        int c = t % 3, h = (t / 3) % 4, side = t / 12;
        const float* att = side ? ad1 : as1;
        float acc = 0.f;
        for (int cc = 0; cc < 32; cc++)
            acc += att[h * 32 + cc] * w1[(h * 32 + cc) * 3 + c];
        qvs[t] = acc;
    }
    __syncthreads();
    // node prep
    int n = b * 256 + tid;
    if (n < N_NODES) {
        float x0 = x[n * 3], x1 = x[n * 3 + 1], x2 = x[n * 3 + 2];
        float s0 = x0 * qvs[0]  + x1 * qvs[1]  + x2 * qvs[2];
        float s1 = x0 * qvs[3]  + x1 * qvs[4]  + x2 * qvs[5];
        float s2 = x0 * qvs[6]  + x1 * qvs[7]  + x2 * qvs[8];
        float s3 = x0 * qvs[9]  + x1 * qvs[10] + x2 * qvs[11];
        float4 d;
        d.x = x0 * qvs[12] + x1 * qvs[13] + x2 * qvs[14];
        d.y = x0 * qvs[15] + x1 * qvs[16] + x2 * qvs[17];
        d.z = x0 * qvs[18] + x1 * qvs[19] + x2 * qvs[20];
        d.w = x0 * qvs[21] + x1 * qvs[22] + x2 * qvs[23];
        ((float4*)a1d)[n] = d;
        __half2 h0 = __floats2half2_rn(s0, s1);
        __half2 h1 = __floats2half2_rn(s2, s3);
        __half2 h2v = __floats2half2_rn(x0, x1);
        __half2 h3 = __floats2half2_rn(x2, 1.f);
        uint4 st;
        st.x = *reinterpret_cast<unsigned int*>(&h0);
        st.y = *reinterpret_cast<unsigned int*>(&h1);
        st.z = *reinterpret_cast<unsigned int*>(&h2v);
        st.w = *reinterpret_cast<unsigned int*>(&h3);
        *reinterpret_cast<uint4*>(p1h + n * 8) = st;
    }
    // histogram
    int base = b * CHUNK;
    #pragma unroll
    for (int i = 0; i < CHUNK / 256; i++) {
        int e = base + i * 256 + tid;
        if (e < N_EDGES) {
            int dst = ei[N_EDGES + e];
            atomicAdd(&hist[dst >> 9], 1);
        }
    }
    __syncthreads();
    if (tid < NBUCK) bh[b * NBUCK + tid] = hist[tid];
}

// ---------------------------------------------------------------- S1: column scan of bh (one block per bucket)
// bh[j][k] -> exclusive per-column offsets; bucketTot[k] = column total (raw, no kS2)
__global__ void kS1(int* __restrict__ bh, int* __restrict__ bucketTot) {
    __shared__ int tsum[256];
    int k = blockIdx.x, t = threadIdx.x;
    int j0 = 2 * t, j1 = 2 * t + 1;
    int v0 = (j0 < BLKB) ? bh[j0 * NBUCK + k] : 0;
    int v1 = (j1 < BLKB) ? bh[j1 * NBUCK + k] : 0;
    int s = v0 + v1;
    tsum[t] = s;
    __syncthreads();
    for (int off = 1; off < 256; off <<= 1) {
        int tv = (t >= off) ? tsum[t - off] : 0;
        __syncthreads();
        tsum[t] += tv;
        __syncthreads();
    }
    int excl = tsum[t] - s;
    if (j0 < BLKB) bh[j0 * NBUCK + k] = excl;
    if (j1 < BLKB) bh[j1 * NBUCK + k] = excl + v0;
    if (t == 255) bucketTot[k] = tsum[255];
}

// ---------------------------------------------------------------- Pass B: bin edges by coarse bucket (self-scans bucket totals)
__global__ void kB_bin(const int* __restrict__ ei, const int* __restrict__ bh,
                       const int* __restrict__ bucketTot, int* __restrict__ binned) {
    __shared__ int cur[NBUCK];
    __shared__ int tmp[256];
    int tid = threadIdx.x, b = blockIdx.x;
    int v = (tid < NBUCK) ? bucketTot[tid] : 0;
    tmp[tid] = v;
    __syncthreads();
    for (int off = 1; off < 256; off <<= 1) {
        int tv = (tid >= off) ? tmp[tid - off] : 0;
        __syncthreads();
        tmp[tid] += tv;
        __syncthreads();
    }
    if (tid < NBUCK) cur[tid] = (tmp[tid] - v) + bh[b * NBUCK + tid];
    __syncthreads();
    int base = b * CHUNK;
    #pragma unroll
    for (int i = 0; i < CHUNK / 256; i++) {
        int e = base + i * 256 + tid;
        if (e < N_EDGES) {
            int src = ei[e], dst = ei[N_EDGES + e];
            int pos = atomicAdd(&cur[dst >> 9], 1);
            binned[pos] = src | ((dst & 511) << 17);
        }
    }
}

// ---------------------------------------------------------------- Pass C: per-bucket counting sort (LDS-staged, single binned read)
__global__ void kC_sort(const int* __restrict__ bucketTot, const int* __restrict__ binned,
                        int* __restrict__ deg, int* __restrict__ rowptr,
                        int* __restrict__ csr_src) {
    __shared__ int ebuf[EBUF_CAP];
    __shared__ int cnt[512];
    __shared__ int pfx[512];
    __shared__ int bsum[256];
    __shared__ int tmp[256];
    int t = threadIdx.x, k = blockIdx.x;
    int v = (t < NBUCK) ? bucketTot[t] : 0;
    tmp[t] = v;
    __syncthreads();
    for (int off = 1; off < 256; off <<= 1) {
        int tv = (t >= off) ? tmp[t - off] : 0;
        __syncthreads();
        tmp[t] += tv;
        __syncthreads();
    }
    int tot = bucketTot[k];
    int s0 = tmp[k] - tot, s1 = s0 + tot;    // tmp[k] broadcast (same-address)
    cnt[t] = 0; cnt[t + 256] = 0;
    __syncthreads();
    int m = s1 - s0;
    bool inl = (m <= EBUF_CAP);
    if (inl) {
        for (int i = t; i < m; i += 256) {
            int pkd = binned[s0 + i];
            ebuf[i] = pkd;
            atomicAdd(&cnt[pkd >> 17], 1);
        }
    } else {
        for (int i = s0 + t; i < s1; i += 256)
            atomicAdd(&cnt[binned[i] >> 17], 1);
    }
    __syncthreads();
    int a0 = cnt[2 * t], a1 = cnt[2 * t + 1];
    int s = a0 + a1;
    bsum[t] = s;
    __syncthreads();
    for (int off = 1; off < 256; off <<= 1) {
        int tv = (t >= off) ? bsum[t - off] : 0;
        __syncthreads();
        bsum[t] += tv;
        __syncthreads();
    }
    int excl = bsum[t] - s;
    pfx[2 * t] = excl;
    pfx[2 * t + 1] = excl + a0;
    int nb0 = k << 9;
    int n0 = nb0 + 2 * t, n1 = nb0 + 2 * t + 1;
    if (n0 < N_NODES) { deg[n0] = a0; rowptr[n0] = s0 + excl; }
    if (n1 < N_NODES) { deg[n1] = a1; rowptr[n1] = s0 + excl + a0; }
    __syncthreads();
    if (inl) {
        for (int i = t; i < m; i += 256) {
            int pkd = ebuf[i];
            int pos = s0 + atomicAdd(&pfx[pkd >> 17], 1);
            csr_src[pos] = pkd & 0x1FFFF;
        }
    } else {
        for (int i = s0 + t; i < s1; i += 256) {
            int pkd = binned[i];
            int pos = s0 + atomicAdd(&pfx[pkd >> 17], 1);
            csr_src[pos] = pkd & 0x1FFFF;
        }
    }
}

// ---------------------------------------------------------------- K-GAT1 v7: fp16 p1 rows (1 gather/edge) + MFMA phase B
#define G1_BLOCKS ((N_NODES + 63) / 64)
__global__ void k_gat1(const int* __restrict__ rowptr, const int* __restrict__ deg,
                       const int* __restrict__ csr_src,
                       const __half* __restrict__ p1h, const float* __restrict__ w1,
                       const float* __restrict__ a1d,
                       const float* __restrict__ b1, const float* __restrict__ w2,
                       const float* __restrict__ as2, const float* __restrict__ ad2,
                       __half* __restrict__ h2, float* __restrict__ a2s, float* __restrict__ a2d) {
    __shared__ float sm[64][16];                        // per-node: 4 heads x {s0,s1,s2,den}
    __shared__ __align__(16) __half F1h[4][16][136];    // per-wave f1, fp16, padded rows
    int tid = threadIdx.x;
    int wave = tid >> 6, lane = tid & 63;

    // ---- phase A: node = block*64 + wave*16 + (lane>>2); lane&3 = edge phase = head slot
    int nl = wave * 16 + (lane >> 2);
    int h  = lane & 3;
    int n  = blockIdx.x * 64 + nl;
    if (n < N_NODES) {
        float4 ad4 = ((const float4*)a1d)[n];          // broadcast across the quad
        float adv[4] = {ad4.x, ad4.y, ad4.z, ad4.w};
        int beg = rowptr[n], cnt = deg[n];
        float acc[4][4];                                // [head][{s0,s1,s2,den}]
        #pragma unroll
        for (int hh = 0; hh < 4; hh++)
            acc[hh][0] = acc[hh][1] = acc[hh][2] = acc[hh][3] = 0.f;
        int t = h;
        for (; t + 12 < cnt; t += 16) {                 // 4 edges/iter, 4 gathers in flight
            int i0 = csr_src[beg + t],     i1 = csr_src[beg + t + 4];
            int i2 = csr_src[beg + t + 8], i3 = csr_src[beg + t + 12];
            float g0[8], g1[8], g2[8], g3[8];
            ld8h(p1h + i0 * 8, g0);
            ld8h(p1h + i1 * 8, g1);
            ld8h(p1h + i2 * 8, g2);
            ld8h(p1h + i3 * 8, g3);
            #pragma unroll
            for (int hh = 0; hh < 4; hh++) {
                float e0 = __expf(lrelu(g0[hh] + adv[hh]));
                float e1 = __expf(lrelu(g1[hh] + adv[hh]));
                float e2 = __expf(lrelu(g2[hh] + adv[hh]));
                float e3 = __expf(lrelu(g3[hh] + adv[hh]));
                acc[hh][0] += e0 * g0[4] + e1 * g1[4] + e2 * g2[4] + e3 * g3[4];
                acc[hh][1] += e0 * g0[5] + e1 * g1[5] + e2 * g2[5] + e3 * g3[5];
                acc[hh][2] += e0 * g0[6] + e1 * g1[6] + e2 * g2[6] + e3 * g3[6];
                acc[hh][3] += e0 + e1 + e2 + e3;
            }
        }
        for (; t < cnt; t += 4) {                       // tail: up to 3 edges per lane
            int i0 = csr_src[beg + t];
            float g0[8];
            ld8h(p1h + i0 * 8, g0);
            #pragma unroll
            for (int hh = 0; hh < 4; hh++) {
                float e0 = __expf(lrelu(g0[hh] + adv[hh]));
                acc[hh][0] += e0 * g0[4];
                acc[hh][1] += e0 * g0[5];
                acc[hh][2] += e0 * g0[6];
                acc[hh][3] += e0;
            }
        }
        // 4-lane butterfly (quad is exec-uniform: same n) — every lane gets full sums
        #pragma unroll
        for (int hh = 0; hh < 4; hh++) {
            #pragma unroll
            for (int cc = 0; cc < 4; cc++) {
                float vv = acc[hh][cc];
                vv += __shfl_xor(vv, 1);
                vv += __shfl_xor(vv, 2);
                acc[hh][cc] = vv;
            }
        }
        float4 r;   // lane writes its own head's slice (static-index select, once per node)
        r.x = h == 0 ? acc[0][0] : h == 1 ? acc[1][0] : h == 2 ? acc[2][0] : acc[3][0];
        r.y = h == 0 ? acc[0][1] : h == 1 ? acc[1][1] : h == 2 ? acc[2][1] : acc[3][1];
        r.z = h == 0 ? acc[0][2] : h == 1 ? acc[1][2] : h == 2 ? acc[2][2] : acc[3][2];
        r.w = h == 0 ? acc[0][3] : h == 1 ? acc[1][3] : h == 2 ? acc[2][3] : acc[3][3];
        *(float4*)&sm[nl][h * 4] = r;
    }
    // same-wave LDS write->read below: no barrier needed

    // ---- B-fragments: Bf[tile][ks], lane elem e = w2[tile*16+(lane&15)][ks*32+(lane>>4)*8+e]
    f16x8 Bf[2][4];
    {
        int bn = lane & 15, bg = lane >> 4;
        #pragma unroll
        for (int tile = 0; tile < 2; tile++) {
            const float* wrow = w2 + (tile * 16 + bn) * 128 + bg * 8;
            #pragma unroll
            for (int ks = 0; ks < 4; ks++) {
                const float4* wp = (const float4*)(wrow + ks * 32);
                float4 u0 = wp[0], u1 = wp[1];
                f16x8 bf;
                bf[0] = (_Float16)u0.x; bf[1] = (_Float16)u0.y;
                bf[2] = (_Float16)u0.z; bf[3] = (_Float16)u0.w;
                bf[4] = (_Float16)u1.x; bf[5] = (_Float16)u1.y;
                bf[6] = (_Float16)u1.z; bf[7] = (_Float16)u1.w;
                Bf[tile][ks] = bf;
            }
        }
    }

    // ---- phase B step 1: f1 (fp16) for the wave's 16 nodes -> F1h
    int j = lane, j2 = lane + 64;
    int h0 = j >> 5;
    float wa0 = w1[j * 3], wa1 = w1[j * 3 + 1], wa2 = w1[j * 3 + 2];
    float wb0 = w1[j2 * 3], wb1 = w1[j2 * 3 + 1], wb2 = w1[j2 * 3 + 2];
    float b1j = b1[j], b1j2 = b1[j2];

    #pragma unroll 1
    for (int i = 0; i < 16; i++) {
        int n2 = blockIdx.x * 64 + wave * 16 + i;
        if (n2 >= N_NODES) break;
        const float* S = sm[wave * 16 + i];
        float v0 = (wa0 * S[h0 * 4] + wa1 * S[h0 * 4 + 1] + wa2 * S[h0 * 4 + 2])
                   / (S[h0 * 4 + 3] + EPS) + b1j;
        float v1 = (wb0 * S[(2 + h0) * 4] + wb1 * S[(2 + h0) * 4 + 1] + wb2 * S[(2 + h0) * 4 + 2])
                   / (S[(2 + h0) * 4 + 3] + EPS) + b1j2;
        float e0 = v0 > 0.f ? v0 : __expf(v0) - 1.f;   // ELU via fast exp
        float e1 = v1 > 0.f ? v1 : __expf(v1) - 1.f;
        F1h[wave][i][j]  = __float2half(e0);
        F1h[wave][i][j2] = __float2half(e1);
    }

    // ---- phase B step 2: 8 MFMA (2 col-tiles x 4 K-steps); A-frag via ds_read_b128
    f32x4 d0 = {0.f, 0.f, 0.f, 0.f}, d1 = {0.f, 0.f, 0.f, 0.f};
    {
        int am = lane & 15, ag = lane >> 4;
        const __half* Arow = &F1h[wave][am][0];
        #pragma unroll
        for (int ks = 0; ks < 4; ks++) {
            f16x8 af = *(const f16x8*)&Arow[ks * 32 + ag * 8];   // 16B-aligned
            d0 = __builtin_amdgcn_mfma_f32_16x16x32_f16(af, Bf[0][ks], d0, 0, 0, 0);
            d1 = __builtin_amdgcn_mfma_f32_16x16x32_f16(af, Bf[1][ks], d1, 0, 0, 0);
        }
    }

    // ---- epilogue: D col = lane&15 (channel), row = (lane>>4)*4+r (node)
    {
        int ch = lane & 15, rg = lane >> 4;
        float as2a = as2[ch], as2b = as2[ch + 16];
        float ad2a = ad2[ch], ad2b = ad2[ch + 16];
        #pragma unroll
        for (int r = 0; r < 4; r++) {
            int n2 = blockIdx.x * 64 + wave * 16 + rg * 4 + r;
            float va = d0[r], vb = d1[r];
            if (n2 < N_NODES) {
                h2[n2 * 32 + ch]      = __float2half(va);
                h2[n2 * 32 + ch + 16] = __float2half(vb);
            }
            float ps = va * as2a + vb * as2b;
            float pd = va * ad2a + vb * ad2b;
            ps += __shfl_xor(ps, 1); ps += __shfl_xor(ps, 2);
            ps += __shfl_xor(ps, 4); ps += __shfl_xor(ps, 8);
            pd += __shfl_xor(pd, 1); pd += __shfl_xor(pd, 2);
            pd += __shfl_xor(pd, 4); pd += __shfl_xor(pd, 8);
            if (ch == 0 && n2 < N_NODES) { a2s[n2] = ps; a2d[n2] = pd; }
        }
    }
}

// ---------------------------------------------------------------- K-GAT2 v6: bank-conflict-free LDS layouts
#define G2_BLOCKS ((N_NODES + 15) / 16)
__global__ void k_gat2(const int* __restrict__ rowptr, const int* __restrict__ deg,
                       const int* __restrict__ csr_src,
                       const __half* __restrict__ h2, const float* __restrict__ a2s,
                       const float* __restrict__ a2d, const float* __restrict__ b2,
                       const float* __restrict__ mw1, const float* __restrict__ mb1,
                       __half* __restrict__ u, __half* __restrict__ v) {
    __shared__ __align__(16) float WT[32][68];  // WT[k][slot]: slot s = half*32+c -> mw1[c][half*32+k]
    __shared__ int   pidx[4][68];               // per-wave staged idx, group stride 17
    __shared__ float pe[4][68];                 // per-wave staged e,   group stride 17
    __shared__ float hfv[4][144];               // per-wave hf, group row stride 36
    int tid = threadIdx.x;
    for (int i = tid; i < 2048; i += 256) {
        int s = i >> 5, k = i & 31;
        WT[k][s] = mw1[(s & 31) * 64 + (s >> 5) * 32 + k];
    }
    __syncthreads();
    int lane = tid & 63, w = tid >> 6;
    int nl = lane >> 4, sl = lane & 15;          // group (node) / sub-lane
    int eg2 = sl >> 2, qq = sl & 3;              // edge slot / 16-B chunk
    int n = blockIdx.x * 16 + w * 4 + nl;        // one node per group, no stride loop
    float4 b2a = ((const float4*)b2)[qq * 2];    // channels qq*8 .. qq*8+3
    float4 b2b = ((const float4*)b2)[qq * 2 + 1];// channels qq*8+4 .. qq*8+7

    int beg = 0, cnt = 0;
    float ad = 0.f;
    if (n < N_NODES) { beg = rowptr[n]; cnt = deg[n]; ad = a2d[n]; }

    float acc[8] = {0.f, 0.f, 0.f, 0.f, 0.f, 0.f, 0.f, 0.f};
    float den = 0.f;
    int pkbase = nl * 17;
    for (int b16 = 0; b16 < cnt; b16 += 16) {    // group-divergent, exec-masked
        int li = b16 + sl;
        int idx = (li < cnt) ? csr_src[beg + li] : 0;
        float e = 0.f;
        if (li < cnt) e = __expf(lrelu(a2s[idx] + ad));
        den += e;
        pidx[w][pkbase + sl] = idx;              // same-wave stage (<=2-way banks)
        pe[w][pkbase + sl]   = e;
        #pragma unroll
        for (int p = 0; p < 4; p++) {            // fixed 4 steps: 4 rows in flight/group
            int id = pidx[w][pkbase + p * 4 + eg2];
            float ee = pe[w][pkbase + p * 4 + eg2];  // 0 for pads
            float g[8];
            ld8h(h2 + id * 32 + qq * 8, g);      // 16-B gather (8 halfs)
            acc[0] += ee * g[0]; acc[1] += ee * g[1];
            acc[2] += ee * g[2]; acc[3] += ee * g[3];
            acc[4] += ee * g[4]; acc[5] += ee * g[5];
            acc[6] += ee * g[6]; acc[7] += ee * g[7];
        }
    }
    // reduce across the 4 edge slots (within 16-lane group)
    #pragma unroll
    for (int j = 0; j < 8; j++) {
        float vv = acc[j];
        vv += __shfl_xor(vv, 4);
        vv += __shfl_xor(vv, 8);
        acc[j] = vv;
    }
    den += __shfl_xor(den, 1); den += __shfl_xor(den, 2);
    den += __shfl_xor(den, 4); den += __shfl_xor(den, 8);
    float inv = 1.f / (den + EPS);
    if (sl < 4) {                                // sl<4 => eg2=0, qq=sl: owns hf[qq*8..+7]
        float4 ha, hb;
        ha.x = acc[0] * inv + b2a.x; ha.y = acc[1] * inv + b2a.y;
        ha.z = acc[2] * inv + b2a.z; ha.w = acc[3] * inv + b2a.w;
        hb.x = acc[4] * inv + b2b.x; hb.y = acc[5] * inv + b2b.y;
        hb.z = acc[6] * inv + b2b.z; hb.w = acc[7] * inv + b2b.w;
        *(float4*)&hfv[w][nl * 36 + sl * 8]     = ha;   // same-wave stage
        *(float4*)&hfv[w][nl * 36 + sl * 8 + 4] = hb;
    }
    // epilogue: lane sl owns output slots 4sl..4sl+3 (slot = half*32 + c)
    if (n < N_NODES) {
        int half_o = sl >> 3, c4 = (sl & 7) * 4;
        __half* outp = half_o ? v : u;
        float r0 = half_o ? 0.f : mb1[c4 + 0];
        float r1 = half_o ? 0.f : mb1[c4 + 1];
        float r2 = half_o ? 0.f : mb1[c4 + 2];
        float r3 = half_o ? 0.f : mb1[c4 + 3];
        const float* hfp = &hfv[w][nl * 36];
        int s4 = sl * 4;                         // slot base
        #pragma unroll
        for (int k = 0; k < 32; k++) {
            float hk = hfp[k];                   // group broadcast (4nl bank offset)
            float4 wv = *(const float4*)&WT[k][s4];  // consecutive slots: 2-way max
            r0 += wv.x * hk; r1 += wv.y * hk;
            r2 += wv.z * hk; r3 += wv.w * hk;
        }
        __half2 p0, p1;
        p0.x = __float2half(r0); p0.y = __float2half(r1);
        p1.x = __float2half(r2); p1.y = __float2half(r3);
        uint2 st;
        st.x = *reinterpret_cast<unsigned int*>(&p0);
        st.y = *reinterpret_cast<unsigned int*>(&p1);
        *reinterpret_cast<uint2*>(outp + n * 32 + c4) = st;  // 8-B aligned store
    }
}

// ---------------------------------------------------------------- K-MLP: 8 lanes/edge, 4 edges/iter, fp16 u/v rows (1 line each)
#define MLP_BLOCKS 4096
__global__ void k_mlp(const int* __restrict__ ei, const __half* __restrict__ u,
                      const __half* __restrict__ v, const float* __restrict__ mw2,
                      const float* __restrict__ mb2, float* __restrict__ out) {
    int tid = threadIdx.x;
    int q = tid & 7;
    float4 w2q = ((const float4*)mw2)[q];
    float mb20 = mb2[0];
    int g = blockIdx.x * 32 + (tid >> 3);
    const int stride = MLP_BLOCKS * 32 * 4;
    for (int e = g * 4; e < N_EDGES; e += stride) {
        int eb = e;
        int e1 = (eb + 1 < N_EDGES) ? eb + 1 : eb;
        int e2 = (eb + 2 < N_EDGES) ? eb + 2 : eb;
        int e3 = (eb + 3 < N_EDGES) ? eb + 3 : eb;
        int sa = ei[eb], da = ei[N_EDGES + eb];
        int sb = ei[e1], db = ei[N_EDGES + e1];
        int sc = ei[e2], dc = ei[N_EDGES + e2];
        int sd = ei[e3], dd = ei[N_EDGES + e3];
        float4 ua = ld4h(u + sa * 32 + q * 4);
        float4 va = ld4h(v + da * 32 + q * 4);
        float4 ub = ld4h(u + sb * 32 + q * 4);
        float4 vb = ld4h(v + db * 32 + q * 4);
        float4 uc = ld4h(u + sc * 32 + q * 4);
        float4 vc = ld4h(v + dc * 32 + q * 4);
        float4 ud = ld4h(u + sd * 32 + q * 4);
        float4 vd = ld4h(v + dd * 32 + q * 4);
        float s0 = fmaxf(ua.x + va.x, 0.f) * w2q.x + fmaxf(ua.y + va.y, 0.f) * w2q.y
                 + fmaxf(ua.z + va.z, 0.f) * w2q.z + fmaxf(ua.w + va.w, 0.f) * w2q.w;
        float s1 = fmaxf(ub.x + vb.x, 0.f) * w2q.x + fmaxf(ub.y + vb.y, 0.f) * w2q.y
                 + fmaxf(ub.z + vb.z, 0.f) * w2q.z + fmaxf(ub.w + vb.w, 0.f) * w2q.w;
        float s2 = fmaxf(uc.x + vc.x, 0.f) * w2q.x + fmaxf(uc.y + vc.y, 0.f) * w2q.y
                 + fmaxf(uc.z + vc.z, 0.f) * w2q.z + fmaxf(uc.w + vc.w, 0.f) * w2q.w;
        float s3 = fmaxf(ud.x + vd.x, 0.f) * w2q.x + fmaxf(ud.y + vd.y, 0.f) * w2q.y
                 + fmaxf(ud.z + vd.z, 0.f) * w2q.z + fmaxf(ud.w + vd.w, 0.f) * w2q.w;
        s0 += __shfl_xor(s0, 1, 8); s0 += __shfl_xor(s0, 2, 8); s0 += __shfl_xor(s0, 4, 8);
        s1 += __shfl_xor(s1, 1, 8); s1 += __shfl_xor(s1, 2, 8); s1 += __shfl_xor(s1, 4, 8);
        s2 += __shfl_xor(s2, 1, 8); s2 += __shfl_xor(s2, 2, 8); s2 += __shfl_xor(s2, 4, 8);
        s3 += __shfl_xor(s3, 1, 8); s3 += __shfl_xor(s3, 2, 8); s3 += __shfl_xor(s3, 4, 8);
        if (q == 0) {
            out[eb] = fmaxf(s0 + mb20, 0.f);
            if (eb + 1 < N_EDGES) out[eb + 1] = fmaxf(s1 + mb20, 0.f);
            if (eb + 2 < N_EDGES) out[eb + 2] = fmaxf(s2 + mb20, 0.f);
            if (eb + 3 < N_EDGES) out[eb + 3] = fmaxf(s3 + mb20, 0.f);
        }
    }
}

// ---------------------------------------------------------------- launch
extern "C" void kernel_launch(void* const* d_in, const int* in_sizes, int n_in,
                              void* d_out, int out_size, void* d_ws, size_t ws_size,
                              hipStream_t stream) {
    const float* x    = (const float*)d_in[0];
    const int*   ei   = (const int*)d_in[1];
    const float* w1   = (const float*)d_in[2];
    const float* as1  = (const float*)d_in[3];
    const float* ad1  = (const float*)d_in[4];
    const float* b1   = (const float*)d_in[5];
    const float* w2   = (const float*)d_in[6];
    const float* as2  = (const float*)d_in[7];
    const float* ad2  = (const float*)d_in[8];
    const float* b2   = (const float*)d_in[9];
    const float* mw1  = (const float*)d_in[10];
    const float* mb1  = (const float*)d_in[11];
    const float* mw2  = (const float*)d_in[12];
    const float* mb2  = (const float*)d_in[13];
    float* out = (float*)d_out;

    // byte-offset workspace layout; p1h/h2/u/v 64B-aligned (offsets verified)
    char* base   = (char*)d_ws;
    int* deg     = (int*)(base);                      // N*4
    int* rowptr  = (int*)(base + 400000);             // N*4
    int* btot    = (int*)(base + 800000);             // NBUCK*4 (raw bucket totals)
    int* bh      = (int*)(base + 1200000);            // BLKB*NBUCK*4 = 306,544 B
    int* csr_src = (int*)(base + 1602048);            // E*4
    __half* p1h  = (__half*)(base + 8002048);         // 8N*2   (%64==0)
    float* a1d   = (float*)(base + 11202048);         // 4N*4
    __half* h2   = (__half*)(base + 12802048);        // 32N*2  (%64==0)
    int* binned  = (int*)(base + 19202048);           // E*4 (disjoint lifetime vs h2 region tail)
    float* a2s   = (float*)(base + 25602048);         // N*4
    float* a2d   = (float*)(base + 26002048);         // N*4
    __half* u    = (__half*)(base + 26402048);        // 32N*2  (%64==0)
    __half* v    = (__half*)(base + 32802048);        // 32N*2  (%64==0)

    kA_hist_node<<<BLKB, 256, 0, stream>>>(ei, bh, x, w1, as1, ad1, a1d, p1h);
    kS1<<<NBUCK, 256, 0, stream>>>(bh, btot);
    kB_bin<<<BLKB, 256, 0, stream>>>(ei, bh, btot, binned);
    kC_sort<<<NBUCK, 256, 0, stream>>>(btot, binned, deg, rowptr, csr_src);

    k_gat1<<<G1_BLOCKS, 256, 0, stream>>>(rowptr, deg, csr_src, p1h, w1, a1d,
                                          b1, w2, as2, ad2, h2, a2s, a2d);

    k_gat2<<<G2_BLOCKS, 256, 0, stream>>>(rowptr, deg, csr_src, h2, a2s, a2d, b2,
                                          mw1, mb1, u, v);

    k_mlp<<<MLP_BLOCKS, 256, 0, stream>>>(ei, u, v, mw2, mb2, out);
}